// Round 1
// baseline (262.582 us; speedup 1.0000x reference)
//
#include <hip/hip_runtime.h>
#include <stdint.h>

typedef short bf16x8 __attribute__((ext_vector_type(8)));
typedef float f32x4  __attribute__((ext_vector_type(4)));

#define LOG2E_F 1.4426950408889634f

__device__ __forceinline__ unsigned short f2bf(float f) {
    unsigned int u = __float_as_uint(f);
    return (unsigned short)((u + 0x7FFFu + ((u >> 16) & 1u)) >> 16);
}

__device__ __forceinline__ uint4 pack8(float4 a, float4 b) {
    union { unsigned short us[8]; uint4 v; } p;
    p.us[0] = f2bf(a.x); p.us[1] = f2bf(a.y); p.us[2] = f2bf(a.z); p.us[3] = f2bf(a.w);
    p.us[4] = f2bf(b.x); p.us[5] = f2bf(b.y); p.us[6] = f2bf(b.z); p.us[7] = f2bf(b.w);
    return p.v;
}

// ===================== 1. QKV projection GEMM =====================
// C[r,o] = sum_e X[r,e] * W[wofs+o, e] + bias[wofs+o]; r = t*4+b, o = head*64+d
// z=0: Q (scaled 1/8) -> [bh][t][d]; z=1: K -> [bh][s][d]; z=2: V^T -> [bh][d][s]
__global__ __launch_bounds__(256)
void qkv_proj_kernel(const float* __restrict__ Xq, const float* __restrict__ Xk,
                     const float* __restrict__ Xv, const float* __restrict__ W,
                     const float* __restrict__ bias,
                     unsigned short* __restrict__ Qb, unsigned short* __restrict__ Kb,
                     unsigned short* __restrict__ Vtb)
{
    const int z    = blockIdx.z;
    const float* __restrict__ X = (z == 0) ? Xq : (z == 1) ? Xk : Xv;
    const int row0 = blockIdx.y * 128;
    const int col0 = blockIdx.x * 128;
    const int wofs = z << 10;

    __shared__ __align__(16) unsigned short As[128 * 40]; // 32 + 8 pad
    __shared__ __align__(16) unsigned short Bs[128 * 40];

    const int tid  = threadIdx.x;
    const int lane = tid & 63;
    const int wv   = tid >> 6;
    const int wr   = wv >> 1, wc = wv & 1;

    const f32x4 zero4 = {0.f, 0.f, 0.f, 0.f};
    f32x4 acc[4][4];
#pragma unroll
    for (int m = 0; m < 4; ++m)
#pragma unroll
        for (int n = 0; n < 4; ++n) acc[m][n] = zero4;

    const int srow = tid >> 1;
    const int scol = (tid & 1) << 4;
    const int arow = wr * 64 + (lane & 15);
    const int brow = wc * 64 + (lane & 15);
    const int kof  = (lane >> 4) << 3;

    for (int k0 = 0; k0 < 1024; k0 += 32) {
        __syncthreads();
        {
            const float* pa = X + (size_t)(row0 + srow) * 1024 + k0 + scol;
            float4 a0 = *(const float4*)(pa + 0);
            float4 a1 = *(const float4*)(pa + 4);
            float4 a2 = *(const float4*)(pa + 8);
            float4 a3 = *(const float4*)(pa + 12);
            *(uint4*)&As[srow * 40 + scol]     = pack8(a0, a1);
            *(uint4*)&As[srow * 40 + scol + 8] = pack8(a2, a3);
            const float* pb = W + (size_t)(wofs + col0 + srow) * 1024 + k0 + scol;
            float4 b0 = *(const float4*)(pb + 0);
            float4 b1 = *(const float4*)(pb + 4);
            float4 b2 = *(const float4*)(pb + 8);
            float4 b3 = *(const float4*)(pb + 12);
            *(uint4*)&Bs[srow * 40 + scol]     = pack8(b0, b1);
            *(uint4*)&Bs[srow * 40 + scol + 8] = pack8(b2, b3);
        }
        __syncthreads();

        bf16x8 af[4], bfr[4];
#pragma unroll
        for (int m = 0; m < 4; ++m)
            af[m] = *(const bf16x8*)&As[(arow + m * 16) * 40 + kof];
#pragma unroll
        for (int n = 0; n < 4; ++n)
            bfr[n] = *(const bf16x8*)&Bs[(brow + n * 16) * 40 + kof];
#pragma unroll
        for (int m = 0; m < 4; ++m)
#pragma unroll
            for (int n = 0; n < 4; ++n)
                acc[m][n] = __builtin_amdgcn_mfma_f32_16x16x32_bf16(af[m], bfr[n], acc[m][n], 0, 0, 0);
    }

    // epilogue: C/D layout col=lane&15, row=(lane>>4)*4+reg
    const int ccol = lane & 15;
    const int crow = (lane >> 4) << 2;
#pragma unroll
    for (int n = 0; n < 4; ++n) {
        const int gc   = col0 + wc * 64 + n * 16 + ccol;
        const float bv = bias[wofs + gc];
        const int head = gc >> 6, d = gc & 63;
#pragma unroll
        for (int m = 0; m < 4; ++m) {
#pragma unroll
            for (int r = 0; r < 4; ++r) {
                const int gr = row0 + wr * 64 + m * 16 + crow + r;
                const int t  = gr >> 2, b = gr & 3;
                const int bh = (b << 4) + head;
                float v = acc[m][n][r] + bv;
                if (z == 0)      Qb [((size_t)bh << 16) + ((size_t)t << 6) + d]  = f2bf(v * 0.125f);
                else if (z == 1) Kb [((size_t)bh << 16) + ((size_t)t << 6) + d]  = f2bf(v);
                else             Vtb[((size_t)bh << 16) + ((size_t)d << 10) + t] = f2bf(v);
            }
        }
    }
}

// ===================== 2. flash attention (online softmax) =====================
__global__ __launch_bounds__(256)
void flash_kernel(const unsigned short* __restrict__ Qb, const unsigned short* __restrict__ Kb,
                  const unsigned short* __restrict__ Vtb, const float* __restrict__ attn_mask,
                  const int* __restrict__ padmask, float* __restrict__ m_buf,
                  float* __restrict__ rl_buf, unsigned short* __restrict__ attn_out)
{
    const int bh = blockIdx.y;
    const int b  = bh >> 4, h = bh & 15;
    const int t0 = blockIdx.x << 7;

    __shared__ __align__(16) unsigned short Ks[64 * 72];  // rows=s, cols=d (pad 8)
    __shared__ __align__(16) unsigned short Vs[64 * 72];  // rows=d, cols=s
    __shared__ __align__(16) unsigned short Ps[128 * 72]; // rows=t, cols=s

    const int tid  = threadIdx.x;
    const int lane = tid & 63;
    const int wv   = tid >> 6;
    const int kof  = (lane >> 4) << 3;

    const unsigned short* Qbase = Qb  + ((size_t)bh << 16);
    const unsigned short* Kbase = Kb  + ((size_t)bh << 16);
    const unsigned short* Vbase = Vtb + ((size_t)bh << 16);

    // Q fragments held in registers for the whole kernel
    bf16x8 qf[2][2];
#pragma unroll
    for (int m = 0; m < 2; ++m)
#pragma unroll
        for (int kk = 0; kk < 2; ++kk)
            qf[m][kk] = *(const bf16x8*)(Qbase +
                ((size_t)(t0 + wv * 32 + m * 16 + (lane & 15)) << 6) + kk * 32 + kof);

    const f32x4 zero4 = {0.f, 0.f, 0.f, 0.f};
    f32x4 acco[2][4];
#pragma unroll
    for (int m = 0; m < 2; ++m)
#pragma unroll
        for (int nd = 0; nd < 4; ++nd) acco[m][nd] = zero4;
    float mrow[2][4], lrow[2][4];
#pragma unroll
    for (int m = 0; m < 2; ++m)
#pragma unroll
        for (int r = 0; r < 4; ++r) { mrow[m][r] = -1e30f; lrow[m][r] = 0.f; }

    const int srow_st = tid >> 2;
    const int scol_st = (tid & 3) << 4;

    for (int s0 = 0; s0 < 1024; s0 += 64) {
        __syncthreads();
        {
            const unsigned short* kp = Kbase + ((size_t)(s0 + srow_st) << 6) + scol_st;
            *(uint4*)&Ks[srow_st * 72 + scol_st]     = *(const uint4*)kp;
            *(uint4*)&Ks[srow_st * 72 + scol_st + 8] = *(const uint4*)(kp + 8);
            const unsigned short* vp = Vbase + ((size_t)srow_st << 10) + s0 + scol_st;
            *(uint4*)&Vs[srow_st * 72 + scol_st]     = *(const uint4*)vp;
            *(uint4*)&Vs[srow_st * 72 + scol_st + 8] = *(const uint4*)(vp + 8);
        }
        __syncthreads();

        // scores: per wave 32 t-rows x 64 s-cols
        f32x4 accs[2][4];
#pragma unroll
        for (int m = 0; m < 2; ++m)
#pragma unroll
            for (int n = 0; n < 4; ++n) accs[m][n] = zero4;
#pragma unroll
        for (int n = 0; n < 4; ++n) {
            bf16x8 kf0 = *(const bf16x8*)&Ks[(n * 16 + (lane & 15)) * 72 + kof];
            bf16x8 kf1 = *(const bf16x8*)&Ks[(n * 16 + (lane & 15)) * 72 + 32 + kof];
#pragma unroll
            for (int m = 0; m < 2; ++m) {
                accs[m][n] = __builtin_amdgcn_mfma_f32_16x16x32_bf16(qf[m][0], kf0, accs[m][n], 0, 0, 0);
                accs[m][n] = __builtin_amdgcn_mfma_f32_16x16x32_bf16(qf[m][1], kf1, accs[m][n], 0, 0, 0);
            }
        }

        int pad_s[4];
#pragma unroll
        for (int n = 0; n < 4; ++n)
            pad_s[n] = padmask[(b << 10) + s0 + n * 16 + (lane & 15)];

#pragma unroll
        for (int m = 0; m < 2; ++m) {
            const int trow = t0 + wv * 32 + m * 16 + ((lane >> 4) << 2);
#pragma unroll
            for (int r = 0; r < 4; ++r) {
                const float* mp = attn_mask + (size_t)(trow + r) * 1024 + s0 + (lane & 15);
                float x0 = accs[m][0][r] + mp[0];
                float x1 = accs[m][1][r] + mp[16];
                float x2 = accs[m][2][r] + mp[32];
                float x3 = accs[m][3][r] + mp[48];
                if (pad_s[0]) x0 = -1e30f;
                if (pad_s[1]) x1 = -1e30f;
                if (pad_s[2]) x2 = -1e30f;
                if (pad_s[3]) x3 = -1e30f;
                float tmax = fmaxf(fmaxf(x0, x1), fmaxf(x2, x3));
                tmax = fmaxf(tmax, __shfl_xor(tmax, 1));
                tmax = fmaxf(tmax, __shfl_xor(tmax, 2));
                tmax = fmaxf(tmax, __shfl_xor(tmax, 4));
                tmax = fmaxf(tmax, __shfl_xor(tmax, 8));
                const float mold = mrow[m][r];
                const float mnew = fmaxf(mold, tmax);
                const float scale = exp2f((mold - mnew) * LOG2E_F);
                float p0 = pad_s[0] ? 0.f : exp2f((x0 - mnew) * LOG2E_F);
                float p1 = pad_s[1] ? 0.f : exp2f((x1 - mnew) * LOG2E_F);
                float p2 = pad_s[2] ? 0.f : exp2f((x2 - mnew) * LOG2E_F);
                float p3 = pad_s[3] ? 0.f : exp2f((x3 - mnew) * LOG2E_F);
                float psum = p0 + p1 + p2 + p3;
                psum += __shfl_xor(psum, 1);
                psum += __shfl_xor(psum, 2);
                psum += __shfl_xor(psum, 4);
                psum += __shfl_xor(psum, 8);
                mrow[m][r] = mnew;
                lrow[m][r] = lrow[m][r] * scale + psum;
#pragma unroll
                for (int nd = 0; nd < 4; ++nd) acco[m][nd][r] *= scale;
                const int prow = wv * 32 + m * 16 + ((lane >> 4) << 2) + r;
                Ps[prow * 72 +  0 + (lane & 15)] = f2bf(p0);
                Ps[prow * 72 + 16 + (lane & 15)] = f2bf(p1);
                Ps[prow * 72 + 32 + (lane & 15)] = f2bf(p2);
                Ps[prow * 72 + 48 + (lane & 15)] = f2bf(p3);
            }
        }
        __syncthreads();

        // PV: A = P rows (t), B = V^T rows (d)
#pragma unroll
        for (int kk2 = 0; kk2 < 2; ++kk2) {
            bf16x8 pf[2];
#pragma unroll
            for (int m = 0; m < 2; ++m)
                pf[m] = *(const bf16x8*)&Ps[(wv * 32 + m * 16 + (lane & 15)) * 72 + kk2 * 32 + kof];
#pragma unroll
            for (int nd = 0; nd < 4; ++nd) {
                bf16x8 vf = *(const bf16x8*)&Vs[(nd * 16 + (lane & 15)) * 72 + kk2 * 32 + kof];
#pragma unroll
                for (int m = 0; m < 2; ++m)
                    acco[m][nd] = __builtin_amdgcn_mfma_f32_16x16x32_bf16(pf[m], vf, acco[m][nd], 0, 0, 0);
            }
        }
    }

    // finalize: normalize, write attn_out + per-row stats
#pragma unroll
    for (int m = 0; m < 2; ++m) {
#pragma unroll
        for (int r = 0; r < 4; ++r) {
            const int t = t0 + wv * 32 + m * 16 + ((lane >> 4) << 2) + r;
            const float rl = 1.0f / lrow[m][r];
            if ((lane & 15) == 0) {
                m_buf [(bh << 10) + t] = mrow[m][r];
                rl_buf[(bh << 10) + t] = rl;
            }
#pragma unroll
            for (int nd = 0; nd < 4; ++nd) {
                const int d = nd * 16 + (lane & 15);
                attn_out[((size_t)t * 4 + b) * 1024 + h * 64 + d] = f2bf(acco[m][nd][r] * rl);
            }
        }
    }
}

// ===================== 3. weights_avg (recompute scores, all heads) =====================
__global__ __launch_bounds__(256)
void wavg_kernel(const unsigned short* __restrict__ Qb, const unsigned short* __restrict__ Kb,
                 const float* __restrict__ attn_mask, const int* __restrict__ padmask,
                 const float* __restrict__ m_buf, const float* __restrict__ rl_buf,
                 float* __restrict__ wout)
{
    const int b  = blockIdx.z;
    const int t0 = blockIdx.y << 6;
    const int s0 = blockIdx.x << 6;

    __shared__ __align__(16) unsigned short Qs[64 * 72];
    __shared__ __align__(16) unsigned short Ks2[64 * 72];

    const int tid  = threadIdx.x;
    const int lane = tid & 63;
    const int wv   = tid >> 6;
    const int wr   = wv >> 1, wc = wv & 1;
    const int kof  = (lane >> 4) << 3;
    const int srow_st = tid >> 2;
    const int scol_st = (tid & 3) << 4;

    const int t_base = t0 + wr * 32 + ((lane >> 4) << 2);
    const int s_base = s0 + wc * 32 + (lane & 15);

    int pad2[2];
#pragma unroll
    for (int nn = 0; nn < 2; ++nn) pad2[nn] = padmask[(b << 10) + s_base + nn * 16];

    float maskv[2][2][4];
#pragma unroll
    for (int mm = 0; mm < 2; ++mm)
#pragma unroll
        for (int r = 0; r < 4; ++r)
#pragma unroll
            for (int nn = 0; nn < 2; ++nn)
                maskv[mm][nn][r] = attn_mask[(size_t)(t_base + mm * 16 + r) * 1024 + s_base + nn * 16];

    float wsum[2][2][4];
#pragma unroll
    for (int mm = 0; mm < 2; ++mm)
#pragma unroll
        for (int nn = 0; nn < 2; ++nn)
#pragma unroll
            for (int r = 0; r < 4; ++r) wsum[mm][nn][r] = 0.f;

    for (int h = 0; h < 16; ++h) {
        const int bh = (b << 4) + h;
        __syncthreads();
        {
            const unsigned short* qp = Qb + ((size_t)bh << 16) + ((size_t)(t0 + srow_st) << 6) + scol_st;
            *(uint4*)&Qs[srow_st * 72 + scol_st]     = *(const uint4*)qp;
            *(uint4*)&Qs[srow_st * 72 + scol_st + 8] = *(const uint4*)(qp + 8);
            const unsigned short* kp = Kb + ((size_t)bh << 16) + ((size_t)(s0 + srow_st) << 6) + scol_st;
            *(uint4*)&Ks2[srow_st * 72 + scol_st]     = *(const uint4*)kp;
            *(uint4*)&Ks2[srow_st * 72 + scol_st + 8] = *(const uint4*)(kp + 8);
        }
        __syncthreads();

        float mv[2][4], rlv[2][4];
#pragma unroll
        for (int mm = 0; mm < 2; ++mm)
#pragma unroll
            for (int r = 0; r < 4; ++r) {
                const int t = t_base + mm * 16 + r;
                mv [mm][r] = m_buf [(bh << 10) + t];
                rlv[mm][r] = rl_buf[(bh << 10) + t];
            }

        const f32x4 zero4 = {0.f, 0.f, 0.f, 0.f};
        f32x4 accs[2][2];
#pragma unroll
        for (int mm = 0; mm < 2; ++mm)
#pragma unroll
            for (int nn = 0; nn < 2; ++nn) accs[mm][nn] = zero4;
#pragma unroll
        for (int nn = 0; nn < 2; ++nn) {
            bf16x8 kf0 = *(const bf16x8*)&Ks2[(wc * 32 + nn * 16 + (lane & 15)) * 72 + kof];
            bf16x8 kf1 = *(const bf16x8*)&Ks2[(wc * 32 + nn * 16 + (lane & 15)) * 72 + 32 + kof];
#pragma unroll
            for (int mm = 0; mm < 2; ++mm) {
                bf16x8 qf0 = *(const bf16x8*)&Qs[(wr * 32 + mm * 16 + (lane & 15)) * 72 + kof];
                bf16x8 qf1 = *(const bf16x8*)&Qs[(wr * 32 + mm * 16 + (lane & 15)) * 72 + 32 + kof];
                accs[mm][nn] = __builtin_amdgcn_mfma_f32_16x16x32_bf16(qf0, kf0, accs[mm][nn], 0, 0, 0);
                accs[mm][nn] = __builtin_amdgcn_mfma_f32_16x16x32_bf16(qf1, kf1, accs[mm][nn], 0, 0, 0);
            }
        }
#pragma unroll
        for (int mm = 0; mm < 2; ++mm)
#pragma unroll
            for (int nn = 0; nn < 2; ++nn)
#pragma unroll
                for (int r = 0; r < 4; ++r)
                    if (!pad2[nn]) {
                        float x = accs[mm][nn][r] + maskv[mm][nn][r];
                        wsum[mm][nn][r] += exp2f((x - mv[mm][r]) * LOG2E_F) * rlv[mm][r];
                    }
    }

#pragma unroll
    for (int mm = 0; mm < 2; ++mm)
#pragma unroll
        for (int nn = 0; nn < 2; ++nn)
#pragma unroll
            for (int r = 0; r < 4; ++r)
                wout[((size_t)b << 20) + (size_t)(t_base + mm * 16 + r) * 1024 + s_base + nn * 16]
                    = wsum[mm][nn][r] * 0.0625f;
}

// ===================== 4. out projection GEMM (bf16 A, fp32 out) =====================
__global__ __launch_bounds__(256)
void out_proj_kernel(const unsigned short* __restrict__ A, const float* __restrict__ W,
                     const float* __restrict__ bias, float* __restrict__ out)
{
    const int row0 = blockIdx.y * 128;
    const int col0 = blockIdx.x * 128;

    __shared__ __align__(16) unsigned short As[128 * 40];
    __shared__ __align__(16) unsigned short Bs[128 * 40];

    const int tid  = threadIdx.x;
    const int lane = tid & 63;
    const int wv   = tid >> 6;
    const int wr   = wv >> 1, wc = wv & 1;

    const f32x4 zero4 = {0.f, 0.f, 0.f, 0.f};
    f32x4 acc[4][4];
#pragma unroll
    for (int m = 0; m < 4; ++m)
#pragma unroll
        for (int n = 0; n < 4; ++n) acc[m][n] = zero4;

    const int srow = tid >> 1;
    const int scol = (tid & 1) << 4;
    const int arow = wr * 64 + (lane & 15);
    const int brow = wc * 64 + (lane & 15);
    const int kof  = (lane >> 4) << 3;

    for (int k0 = 0; k0 < 1024; k0 += 32) {
        __syncthreads();
        {
            const unsigned short* pa = A + (size_t)(row0 + srow) * 1024 + k0 + scol;
            *(uint4*)&As[srow * 40 + scol]     = *(const uint4*)pa;
            *(uint4*)&As[srow * 40 + scol + 8] = *(const uint4*)(pa + 8);
            const float* pb = W + (size_t)(col0 + srow) * 1024 + k0 + scol;
            float4 b0 = *(const float4*)(pb + 0);
            float4 b1 = *(const float4*)(pb + 4);
            float4 b2 = *(const float4*)(pb + 8);
            float4 b3 = *(const float4*)(pb + 12);
            *(uint4*)&Bs[srow * 40 + scol]     = pack8(b0, b1);
            *(uint4*)&Bs[srow * 40 + scol + 8] = pack8(b2, b3);
        }
        __syncthreads();

        bf16x8 af[4], bfr[4];
#pragma unroll
        for (int m = 0; m < 4; ++m)
            af[m] = *(const bf16x8*)&As[(arow + m * 16) * 40 + kof];
#pragma unroll
        for (int n = 0; n < 4; ++n)
            bfr[n] = *(const bf16x8*)&Bs[(brow + n * 16) * 40 + kof];
#pragma unroll
        for (int m = 0; m < 4; ++m)
#pragma unroll
            for (int n = 0; n < 4; ++n)
                acc[m][n] = __builtin_amdgcn_mfma_f32_16x16x32_bf16(af[m], bfr[n], acc[m][n], 0, 0, 0);
    }

    const int ccol = lane & 15;
    const int crow = (lane >> 4) << 2;
#pragma unroll
    for (int n = 0; n < 4; ++n) {
        const int gc   = col0 + wc * 64 + n * 16 + ccol;
        const float bv = bias[gc];
#pragma unroll
        for (int m = 0; m < 4; ++m) {
#pragma unroll
            for (int r = 0; r < 4; ++r) {
                const int gr = row0 + wr * 64 + m * 16 + crow + r;
                out[(size_t)gr * 1024 + gc] = acc[m][n][r] + bv;
            }
        }
    }
}

// ===================== host =====================
extern "C" void kernel_launch(void* const* d_in, const int* in_sizes, int n_in,
                              void* d_out, int out_size, void* d_ws, size_t ws_size,
                              hipStream_t stream)
{
    const float* query     = (const float*)d_in[0];
    const float* key       = (const float*)d_in[1];
    const float* value     = (const float*)d_in[2];
    const float* attn_mask = (const float*)d_in[3];
    const int*   padmask   = (const int*)  d_in[4];
    const float* in_proj_w = (const float*)d_in[5];
    const float* in_proj_b = (const float*)d_in[6];
    const float* out_w     = (const float*)d_in[7];
    const float* out_b     = (const float*)d_in[8];

    float* out  = (float*)d_out;
    float* wavg = out + 4194304; // T*B*E

    char* ws = (char*)d_ws;
    unsigned short* Qb     = (unsigned short*)(ws);              // 8 MB  [64][1024][64]
    unsigned short* Kb     = (unsigned short*)(ws + 8388608);    // 8 MB
    unsigned short* Vtb    = (unsigned short*)(ws + 16777216);   // 8 MB  [64][64][1024]
    unsigned short* attn_o = (unsigned short*)(ws + 25165824);   // 8 MB  [4096][1024]
    float*          m_buf  = (float*)(ws + 33554432);            // 256 KB [64][1024]
    float*          rl_buf = (float*)(ws + 33816576);            // 256 KB

    qkv_proj_kernel<<<dim3(8, 32, 3), 256, 0, stream>>>(query, key, value, in_proj_w, in_proj_b,
                                                        Qb, Kb, Vtb);
    flash_kernel<<<dim3(8, 64), 256, 0, stream>>>(Qb, Kb, Vtb, attn_mask, padmask,
                                                  m_buf, rl_buf, attn_o);
    wavg_kernel<<<dim3(16, 16, 4), 256, 0, stream>>>(Qb, Kb, attn_mask, padmask,
                                                     m_buf, rl_buf, wavg);
    out_proj_kernel<<<dim3(8, 32), 256, 0, stream>>>(attn_o, out_w, out_b, out);
}

// Round 2
// 227.795 us; speedup vs baseline: 1.1527x; 1.1527x over previous
//
#include <hip/hip_runtime.h>
#include <stdint.h>

typedef short bf16x8 __attribute__((ext_vector_type(8)));
typedef float f32x4  __attribute__((ext_vector_type(4)));

#define LOG2E_F 1.4426950408889634f
// 0.125 * log2(e): folded into Q so exp2 args need no multiply
#define QSCALE_F 0.1803368801111204f

__device__ __forceinline__ unsigned short f2bf(float f) {
    unsigned int u = __float_as_uint(f);
    return (unsigned short)((u + 0x7FFFu + ((u >> 16) & 1u)) >> 16);
}

__device__ __forceinline__ uint4 pack8(float4 a, float4 b) {
    union { unsigned short us[8]; uint4 v; } p;
    p.us[0] = f2bf(a.x); p.us[1] = f2bf(a.y); p.us[2] = f2bf(a.z); p.us[3] = f2bf(a.w);
    p.us[4] = f2bf(b.x); p.us[5] = f2bf(b.y); p.us[6] = f2bf(b.z); p.us[7] = f2bf(b.w);
    return p.v;
}

// ===================== 1. QKV projection GEMM =====================
// z=0: Q (scaled 0.125*log2e) -> [bh][t][d]; z=1: K -> [bh][s][d]; z=2: V^T -> [bh][d][s]
__global__ __launch_bounds__(256)
void qkv_proj_kernel(const float* __restrict__ Xq, const float* __restrict__ Xk,
                     const float* __restrict__ Xv, const float* __restrict__ W,
                     const float* __restrict__ bias,
                     unsigned short* __restrict__ Qb, unsigned short* __restrict__ Kb,
                     unsigned short* __restrict__ Vtb)
{
    const int z    = blockIdx.z;
    const float* __restrict__ X = (z == 0) ? Xq : (z == 1) ? Xk : Xv;
    const int row0 = blockIdx.y * 128;
    const int col0 = blockIdx.x * 128;
    const int wofs = z << 10;

    __shared__ __align__(16) unsigned short As[128 * 40];
    __shared__ __align__(16) unsigned short Bs[128 * 40];

    const int tid  = threadIdx.x;
    const int lane = tid & 63;
    const int wv   = tid >> 6;
    const int wr   = wv >> 1, wc = wv & 1;

    const f32x4 zero4 = {0.f, 0.f, 0.f, 0.f};
    f32x4 acc[4][4];
#pragma unroll
    for (int m = 0; m < 4; ++m)
#pragma unroll
        for (int n = 0; n < 4; ++n) acc[m][n] = zero4;

    const int srow = tid >> 1;
    const int scol = (tid & 1) << 4;
    const int arow = wr * 64 + (lane & 15);
    const int brow = wc * 64 + (lane & 15);
    const int kof  = (lane >> 4) << 3;

    for (int k0 = 0; k0 < 1024; k0 += 32) {
        __syncthreads();
        {
            const float* pa = X + (size_t)(row0 + srow) * 1024 + k0 + scol;
            float4 a0 = *(const float4*)(pa + 0);
            float4 a1 = *(const float4*)(pa + 4);
            float4 a2 = *(const float4*)(pa + 8);
            float4 a3 = *(const float4*)(pa + 12);
            *(uint4*)&As[srow * 40 + scol]     = pack8(a0, a1);
            *(uint4*)&As[srow * 40 + scol + 8] = pack8(a2, a3);
            const float* pb = W + (size_t)(wofs + col0 + srow) * 1024 + k0 + scol;
            float4 b0 = *(const float4*)(pb + 0);
            float4 b1 = *(const float4*)(pb + 4);
            float4 b2 = *(const float4*)(pb + 8);
            float4 b3 = *(const float4*)(pb + 12);
            *(uint4*)&Bs[srow * 40 + scol]     = pack8(b0, b1);
            *(uint4*)&Bs[srow * 40 + scol + 8] = pack8(b2, b3);
        }
        __syncthreads();

        bf16x8 af[4], bfr[4];
#pragma unroll
        for (int m = 0; m < 4; ++m)
            af[m] = *(const bf16x8*)&As[(arow + m * 16) * 40 + kof];
#pragma unroll
        for (int n = 0; n < 4; ++n)
            bfr[n] = *(const bf16x8*)&Bs[(brow + n * 16) * 40 + kof];
#pragma unroll
        for (int m = 0; m < 4; ++m)
#pragma unroll
            for (int n = 0; n < 4; ++n)
                acc[m][n] = __builtin_amdgcn_mfma_f32_16x16x32_bf16(af[m], bfr[n], acc[m][n], 0, 0, 0);
    }

    const int ccol = lane & 15;
    const int crow = (lane >> 4) << 2;
#pragma unroll
    for (int n = 0; n < 4; ++n) {
        const int gc   = col0 + wc * 64 + n * 16 + ccol;
        const float bv = bias[wofs + gc];
        const int head = gc >> 6, d = gc & 63;
#pragma unroll
        for (int m = 0; m < 4; ++m) {
#pragma unroll
            for (int r = 0; r < 4; ++r) {
                const int gr = row0 + wr * 64 + m * 16 + crow + r;
                const int t  = gr >> 2, b = gr & 3;
                const int bh = (b << 4) + head;
                float v = acc[m][n][r] + bv;
                if (z == 0)      Qb [((size_t)bh << 16) + ((size_t)t << 6) + d]  = f2bf(v * QSCALE_F);
                else if (z == 1) Kb [((size_t)bh << 16) + ((size_t)t << 6) + d]  = f2bf(v);
                else             Vtb[((size_t)bh << 16) + ((size_t)d << 10) + t] = f2bf(v);
            }
        }
    }
}

// ===================== 2. flash attention (online softmax, log2-domain) =====================
// t-tile = 64, 4 waves, each wave owns 16 t-rows. Ps traffic is wave-local -> no 3rd barrier.
__global__ __launch_bounds__(256)
void flash_kernel(const unsigned short* __restrict__ Qb, const unsigned short* __restrict__ Kb,
                  const unsigned short* __restrict__ Vtb, const float* __restrict__ attn_mask,
                  const int* __restrict__ padmask, float* __restrict__ m_buf,
                  float* __restrict__ rl_buf, unsigned short* __restrict__ attn_out)
{
    const int bh = blockIdx.y;
    const int b  = bh >> 4, h = bh & 15;
    const int t0 = blockIdx.x << 6;

    __shared__ __align__(16) unsigned short Ks[64 * 72];  // rows=s, cols=d (pad 8)
    __shared__ __align__(16) unsigned short Vs[64 * 72];  // rows=d, cols=s
    __shared__ __align__(16) unsigned short Ps[64 * 72];  // rows=t (wave-local 16-row slabs)

    const int tid  = threadIdx.x;
    const int lane = tid & 63;
    const int wv   = tid >> 6;
    const int kof  = (lane >> 4) << 3;
    const int c16  = lane & 15;

    const unsigned short* Qbase = Qb  + ((size_t)bh << 16);
    const unsigned short* Kbase = Kb  + ((size_t)bh << 16);
    const unsigned short* Vbase = Vtb + ((size_t)bh << 16);

    bf16x8 qf[2];
#pragma unroll
    for (int kk = 0; kk < 2; ++kk)
        qf[kk] = *(const bf16x8*)(Qbase + ((size_t)(t0 + wv * 16 + c16) << 6) + kk * 32 + kof);

    const f32x4 zero4 = {0.f, 0.f, 0.f, 0.f};
    f32x4 acco[4];
#pragma unroll
    for (int nd = 0; nd < 4; ++nd) acco[nd] = zero4;
    float mrow[4], lrow[4];
#pragma unroll
    for (int r = 0; r < 4; ++r) { mrow[r] = -1e30f; lrow[r] = 0.f; }

    const int srow_st = tid >> 2;
    const int scol_st = (tid & 3) << 4;

    // prefetch tile 0 into registers
    const unsigned short* kp = Kbase + ((size_t)srow_st << 6) + scol_st;
    const unsigned short* vp = Vbase + ((size_t)srow_st << 10) + scol_st;
    uint4 kr0 = *(const uint4*)kp, kr1 = *(const uint4*)(kp + 8);
    uint4 vr0 = *(const uint4*)vp, vr1 = *(const uint4*)(vp + 8);

    for (int s0 = 0; s0 < 1024; s0 += 64) {
        __syncthreads();  // previous tile's LDS reads done
        *(uint4*)&Ks[srow_st * 72 + scol_st]     = kr0;
        *(uint4*)&Ks[srow_st * 72 + scol_st + 8] = kr1;
        *(uint4*)&Vs[srow_st * 72 + scol_st]     = vr0;
        *(uint4*)&Vs[srow_st * 72 + scol_st + 8] = vr1;
        __syncthreads();

        // issue next tile's global loads now; latency hides under compute
        if (s0 < 960) {
            kp = Kbase + ((size_t)(s0 + 64 + srow_st) << 6) + scol_st;
            vp = Vbase + ((size_t)srow_st << 10) + (s0 + 64) + scol_st;
            kr0 = *(const uint4*)kp; kr1 = *(const uint4*)(kp + 8);
            vr0 = *(const uint4*)vp; vr1 = *(const uint4*)(vp + 8);
        }

        // scores: 16 t-rows x 64 s-cols per wave
        f32x4 accs[4];
#pragma unroll
        for (int n = 0; n < 4; ++n) accs[n] = zero4;
#pragma unroll
        for (int n = 0; n < 4; ++n) {
            bf16x8 kf0 = *(const bf16x8*)&Ks[(n * 16 + c16) * 72 + kof];
            bf16x8 kf1 = *(const bf16x8*)&Ks[(n * 16 + c16) * 72 + 32 + kof];
            accs[n] = __builtin_amdgcn_mfma_f32_16x16x32_bf16(qf[0], kf0, accs[n], 0, 0, 0);
            accs[n] = __builtin_amdgcn_mfma_f32_16x16x32_bf16(qf[1], kf1, accs[n], 0, 0, 0);
        }

        int pad_s[4];
#pragma unroll
        for (int n = 0; n < 4; ++n)
            pad_s[n] = padmask[(b << 10) + s0 + n * 16 + c16];

        const int rbase = wv * 16 + ((lane >> 4) << 2);
#pragma unroll
        for (int r = 0; r < 4; ++r) {
            const float* mp = attn_mask + (size_t)(t0 + rbase + r) * 1024 + s0 + c16;
            float x0 = accs[0][r] + mp[ 0] * LOG2E_F;
            float x1 = accs[1][r] + mp[16] * LOG2E_F;
            float x2 = accs[2][r] + mp[32] * LOG2E_F;
            float x3 = accs[3][r] + mp[48] * LOG2E_F;
            if (pad_s[0]) x0 = -1e30f;
            if (pad_s[1]) x1 = -1e30f;
            if (pad_s[2]) x2 = -1e30f;
            if (pad_s[3]) x3 = -1e30f;
            float tmax = fmaxf(fmaxf(x0, x1), fmaxf(x2, x3));
            tmax = fmaxf(tmax, __shfl_xor(tmax, 1));
            tmax = fmaxf(tmax, __shfl_xor(tmax, 2));
            tmax = fmaxf(tmax, __shfl_xor(tmax, 4));
            tmax = fmaxf(tmax, __shfl_xor(tmax, 8));
            const float mold = mrow[r];
            const float mnew = fmaxf(mold, tmax);
            const float scale = exp2f(mold - mnew);
            float p0 = pad_s[0] ? 0.f : exp2f(x0 - mnew);
            float p1 = pad_s[1] ? 0.f : exp2f(x1 - mnew);
            float p2 = pad_s[2] ? 0.f : exp2f(x2 - mnew);
            float p3 = pad_s[3] ? 0.f : exp2f(x3 - mnew);
            float psum = p0 + p1 + p2 + p3;
            psum += __shfl_xor(psum, 1);
            psum += __shfl_xor(psum, 2);
            psum += __shfl_xor(psum, 4);
            psum += __shfl_xor(psum, 8);
            mrow[r] = mnew;
            lrow[r] = lrow[r] * scale + psum;
#pragma unroll
            for (int nd = 0; nd < 4; ++nd) acco[nd][r] *= scale;
            const int prow = rbase + r;
            Ps[prow * 72 +  0 + c16] = f2bf(p0);
            Ps[prow * 72 + 16 + c16] = f2bf(p1);
            Ps[prow * 72 + 32 + c16] = f2bf(p2);
            Ps[prow * 72 + 48 + c16] = f2bf(p3);
        }
        // no barrier: each wave reads only its own Ps rows

#pragma unroll
        for (int kk2 = 0; kk2 < 2; ++kk2) {
            bf16x8 pf = *(const bf16x8*)&Ps[(wv * 16 + c16) * 72 + kk2 * 32 + kof];
#pragma unroll
            for (int nd = 0; nd < 4; ++nd) {
                bf16x8 vf = *(const bf16x8*)&Vs[(nd * 16 + c16) * 72 + kk2 * 32 + kof];
                acco[nd] = __builtin_amdgcn_mfma_f32_16x16x32_bf16(pf, vf, acco[nd], 0, 0, 0);
            }
        }
    }

#pragma unroll
    for (int r = 0; r < 4; ++r) {
        const int t = t0 + wv * 16 + ((lane >> 4) << 2) + r;
        const float rl = 1.0f / lrow[r];
        if (c16 == 0) {
            m_buf [(bh << 10) + t] = mrow[r];
            rl_buf[(bh << 10) + t] = rl;
        }
#pragma unroll
        for (int nd = 0; nd < 4; ++nd) {
            const int d = nd * 16 + c16;
            attn_out[((size_t)t * 4 + b) * 1024 + h * 64 + d] = f2bf(acco[nd][r] * rl);
        }
    }
}

// ===================== 3. weights_avg (recompute scores, all heads) =====================
__global__ __launch_bounds__(256)
void wavg_kernel(const unsigned short* __restrict__ Qb, const unsigned short* __restrict__ Kb,
                 const float* __restrict__ attn_mask, const int* __restrict__ padmask,
                 const float* __restrict__ m_buf, const float* __restrict__ rl_buf,
                 float* __restrict__ wout)
{
    const int b  = blockIdx.z;
    const int t0 = blockIdx.y << 6;
    const int s0 = blockIdx.x << 6;

    __shared__ __align__(16) unsigned short Qs[64 * 72];
    __shared__ __align__(16) unsigned short Ks2[64 * 72];

    const int tid  = threadIdx.x;
    const int lane = tid & 63;
    const int wv   = tid >> 6;
    const int wr   = wv >> 1, wc = wv & 1;
    const int kof  = (lane >> 4) << 3;
    const int srow_st = tid >> 2;
    const int scol_st = (tid & 3) << 4;

    const int t_base = t0 + wr * 32 + ((lane >> 4) << 2);
    const int s_base = s0 + wc * 32 + (lane & 15);

    int pad2[2];
#pragma unroll
    for (int nn = 0; nn < 2; ++nn) pad2[nn] = padmask[(b << 10) + s_base + nn * 16];

    float maskv[2][2][4];
#pragma unroll
    for (int mm = 0; mm < 2; ++mm)
#pragma unroll
        for (int r = 0; r < 4; ++r)
#pragma unroll
            for (int nn = 0; nn < 2; ++nn)
                maskv[mm][nn][r] = attn_mask[(size_t)(t_base + mm * 16 + r) * 1024 + s_base + nn * 16] * LOG2E_F;

    float wsum[2][2][4];
#pragma unroll
    for (int mm = 0; mm < 2; ++mm)
#pragma unroll
        for (int nn = 0; nn < 2; ++nn)
#pragma unroll
            for (int r = 0; r < 4; ++r) wsum[mm][nn][r] = 0.f;

    for (int h = 0; h < 16; ++h) {
        const int bh = (b << 4) + h;
        __syncthreads();
        {
            const unsigned short* qp = Qb + ((size_t)bh << 16) + ((size_t)(t0 + srow_st) << 6) + scol_st;
            *(uint4*)&Qs[srow_st * 72 + scol_st]     = *(const uint4*)qp;
            *(uint4*)&Qs[srow_st * 72 + scol_st + 8] = *(const uint4*)(qp + 8);
            const unsigned short* kp = Kb + ((size_t)bh << 16) + ((size_t)(s0 + srow_st) << 6) + scol_st;
            *(uint4*)&Ks2[srow_st * 72 + scol_st]     = *(const uint4*)kp;
            *(uint4*)&Ks2[srow_st * 72 + scol_st + 8] = *(const uint4*)(kp + 8);
        }
        __syncthreads();

        float mv[2][4], rlv[2][4];
#pragma unroll
        for (int mm = 0; mm < 2; ++mm)
#pragma unroll
            for (int r = 0; r < 4; ++r) {
                const int t = t_base + mm * 16 + r;
                mv [mm][r] = m_buf [(bh << 10) + t];
                rlv[mm][r] = rl_buf[(bh << 10) + t];
            }

        const f32x4 zero4 = {0.f, 0.f, 0.f, 0.f};
        f32x4 accs[2][2];
#pragma unroll
        for (int mm = 0; mm < 2; ++mm)
#pragma unroll
            for (int nn = 0; nn < 2; ++nn) accs[mm][nn] = zero4;
#pragma unroll
        for (int nn = 0; nn < 2; ++nn) {
            bf16x8 kf0 = *(const bf16x8*)&Ks2[(wc * 32 + nn * 16 + (lane & 15)) * 72 + kof];
            bf16x8 kf1 = *(const bf16x8*)&Ks2[(wc * 32 + nn * 16 + (lane & 15)) * 72 + 32 + kof];
#pragma unroll
            for (int mm = 0; mm < 2; ++mm) {
                bf16x8 qf0 = *(const bf16x8*)&Qs[(wr * 32 + mm * 16 + (lane & 15)) * 72 + kof];
                bf16x8 qf1 = *(const bf16x8*)&Qs[(wr * 32 + mm * 16 + (lane & 15)) * 72 + 32 + kof];
                accs[mm][nn] = __builtin_amdgcn_mfma_f32_16x16x32_bf16(qf0, kf0, accs[mm][nn], 0, 0, 0);
                accs[mm][nn] = __builtin_amdgcn_mfma_f32_16x16x32_bf16(qf1, kf1, accs[mm][nn], 0, 0, 0);
            }
        }
#pragma unroll
        for (int mm = 0; mm < 2; ++mm)
#pragma unroll
            for (int nn = 0; nn < 2; ++nn)
#pragma unroll
                for (int r = 0; r < 4; ++r)
                    if (!pad2[nn]) {
                        float x = accs[mm][nn][r] + maskv[mm][nn][r];
                        wsum[mm][nn][r] += exp2f(x - mv[mm][r]) * rlv[mm][r];
                    }
    }

#pragma unroll
    for (int mm = 0; mm < 2; ++mm)
#pragma unroll
        for (int nn = 0; nn < 2; ++nn)
#pragma unroll
            for (int r = 0; r < 4; ++r)
                wout[((size_t)b << 20) + (size_t)(t_base + mm * 16 + r) * 1024 + s_base + nn * 16]
                    = wsum[mm][nn][r] * 0.0625f;
}

// ===================== 4. out projection GEMM (bf16 A, fp32 out) =====================
__global__ __launch_bounds__(256)
void out_proj_kernel(const unsigned short* __restrict__ A, const float* __restrict__ W,
                     const float* __restrict__ bias, float* __restrict__ out)
{
    const int row0 = blockIdx.y * 128;
    const int col0 = blockIdx.x * 128;

    __shared__ __align__(16) unsigned short As[128 * 40];
    __shared__ __align__(16) unsigned short Bs[128 * 40];

    const int tid  = threadIdx.x;
    const int lane = tid & 63;
    const int wv   = tid >> 6;
    const int wr   = wv >> 1, wc = wv & 1;

    const f32x4 zero4 = {0.f, 0.f, 0.f, 0.f};
    f32x4 acc[4][4];
#pragma unroll
    for (int m = 0; m < 4; ++m)
#pragma unroll
        for (int n = 0; n < 4; ++n) acc[m][n] = zero4;

    const int srow = tid >> 1;
    const int scol = (tid & 1) << 4;
    const int arow = wr * 64 + (lane & 15);
    const int brow = wc * 64 + (lane & 15);
    const int kof  = (lane >> 4) << 3;

    for (int k0 = 0; k0 < 1024; k0 += 32) {
        __syncthreads();
        {
            const unsigned short* pa = A + (size_t)(row0 + srow) * 1024 + k0 + scol;
            *(uint4*)&As[srow * 40 + scol]     = *(const uint4*)pa;
            *(uint4*)&As[srow * 40 + scol + 8] = *(const uint4*)(pa + 8);
            const float* pb = W + (size_t)(col0 + srow) * 1024 + k0 + scol;
            float4 b0 = *(const float4*)(pb + 0);
            float4 b1 = *(const float4*)(pb + 4);
            float4 b2 = *(const float4*)(pb + 8);
            float4 b3 = *(const float4*)(pb + 12);
            *(uint4*)&Bs[srow * 40 + scol]     = pack8(b0, b1);
            *(uint4*)&Bs[srow * 40 + scol + 8] = pack8(b2, b3);
        }
        __syncthreads();

        bf16x8 af[4], bfr[4];
#pragma unroll
        for (int m = 0; m < 4; ++m)
            af[m] = *(const bf16x8*)&As[(arow + m * 16) * 40 + kof];
#pragma unroll
        for (int n = 0; n < 4; ++n)
            bfr[n] = *(const bf16x8*)&Bs[(brow + n * 16) * 40 + kof];
#pragma unroll
        for (int m = 0; m < 4; ++m)
#pragma unroll
            for (int n = 0; n < 4; ++n)
                acc[m][n] = __builtin_amdgcn_mfma_f32_16x16x32_bf16(af[m], bfr[n], acc[m][n], 0, 0, 0);
    }

    const int ccol = lane & 15;
    const int crow = (lane >> 4) << 2;
#pragma unroll
    for (int n = 0; n < 4; ++n) {
        const int gc   = col0 + wc * 64 + n * 16 + ccol;
        const float bv = bias[gc];
#pragma unroll
        for (int m = 0; m < 4; ++m) {
#pragma unroll
            for (int r = 0; r < 4; ++r) {
                const int gr = row0 + wr * 64 + m * 16 + crow + r;
                out[(size_t)gr * 1024 + gc] = acc[m][n][r] + bv;
            }
        }
    }
}

// ===================== host =====================
extern "C" void kernel_launch(void* const* d_in, const int* in_sizes, int n_in,
                              void* d_out, int out_size, void* d_ws, size_t ws_size,
                              hipStream_t stream)
{
    const float* query     = (const float*)d_in[0];
    const float* key       = (const float*)d_in[1];
    const float* value     = (const float*)d_in[2];
    const float* attn_mask = (const float*)d_in[3];
    const int*   padmask   = (const int*)  d_in[4];
    const float* in_proj_w = (const float*)d_in[5];
    const float* in_proj_b = (const float*)d_in[6];
    const float* out_w     = (const float*)d_in[7];
    const float* out_b     = (const float*)d_in[8];

    float* out  = (float*)d_out;
    float* wavg = out + 4194304; // T*B*E

    char* ws = (char*)d_ws;
    unsigned short* Qb     = (unsigned short*)(ws);              // 8 MB  [64][1024][64]
    unsigned short* Kb     = (unsigned short*)(ws + 8388608);    // 8 MB
    unsigned short* Vtb    = (unsigned short*)(ws + 16777216);   // 8 MB  [64][64][1024]
    unsigned short* attn_o = (unsigned short*)(ws + 25165824);   // 8 MB  [4096][1024]
    float*          m_buf  = (float*)(ws + 33554432);            // 256 KB [64][1024]
    float*          rl_buf = (float*)(ws + 33816576);            // 256 KB

    qkv_proj_kernel<<<dim3(8, 32, 3), 256, 0, stream>>>(query, key, value, in_proj_w, in_proj_b,
                                                        Qb, Kb, Vtb);
    flash_kernel<<<dim3(16, 64), 256, 0, stream>>>(Qb, Kb, Vtb, attn_mask, padmask,
                                                   m_buf, rl_buf, attn_o);
    wavg_kernel<<<dim3(16, 16, 4), 256, 0, stream>>>(Qb, Kb, attn_mask, padmask,
                                                     m_buf, rl_buf, wavg);
    out_proj_kernel<<<dim3(8, 32), 256, 0, stream>>>(attn_o, out_w, out_b, out);
}

// Round 3
// 194.157 us; speedup vs baseline: 1.3524x; 1.1733x over previous
//
#include <hip/hip_runtime.h>
#include <stdint.h>

typedef short bf16x8 __attribute__((ext_vector_type(8)));
typedef float f32x4  __attribute__((ext_vector_type(4)));

#define LOG2E_F 1.4426950408889634f
// 0.125 * log2(e): folded into Q so exp2 args need no multiply
#define QSCALE_F 0.1803368801111204f

__device__ __forceinline__ unsigned short f2bf(float f) {
    unsigned int u = __float_as_uint(f);
    return (unsigned short)((u + 0x7FFFu + ((u >> 16) & 1u)) >> 16);
}

__device__ __forceinline__ uint4 pack8(float4 a, float4 b) {
    union { unsigned short us[8]; uint4 v; } p;
    p.us[0] = f2bf(a.x); p.us[1] = f2bf(a.y); p.us[2] = f2bf(a.z); p.us[3] = f2bf(a.w);
    p.us[4] = f2bf(b.x); p.us[5] = f2bf(b.y); p.us[6] = f2bf(b.z); p.us[7] = f2bf(b.w);
    return p.v;
}

// ===================== 0. f32 -> bf16 convert (X, in_proj_w, out_w) =====================
// group = 8 elements. q/k/v: 524288 groups each -> Xb concat; w: 393216 -> Wb; ow: 131072 -> OWb.
__global__ __launch_bounds__(256)
void cvt_kernel(const float* __restrict__ q, const float* __restrict__ k,
                const float* __restrict__ v, const float* __restrict__ w,
                const float* __restrict__ ow,
                uint4* __restrict__ Xb, uint4* __restrict__ Wb, uint4* __restrict__ OWb)
{
    const unsigned g = blockIdx.x * 256 + threadIdx.x;   // 0 .. 2097151
    const float* src;
    uint4* dst;
    if (g < 1572864u) {
        dst = Xb + g;
        if (g < 524288u)        src = q + (size_t)g * 8;
        else if (g < 1048576u)  src = k + (size_t)(g - 524288u) * 8;
        else                    src = v + (size_t)(g - 1048576u) * 8;
    } else if (g < 1966080u) {
        src = w + (size_t)(g - 1572864u) * 8;
        dst = Wb + (g - 1572864u);
    } else {
        src = ow + (size_t)(g - 1966080u) * 8;
        dst = OWb + (g - 1966080u);
    }
    float4 a = *(const float4*)src;
    float4 b = *(const float4*)(src + 4);
    *dst = pack8(a, b);
}

// ===================== 1. QKV projection GEMM (bf16 in, BK=64, prefetch) =====================
// z=0: Q (scaled 0.125*log2e) -> [bh][t][d]; z=1: K -> [bh][s][d]; z=2: V^T -> [bh][d][s]
__global__ __launch_bounds__(256)
void qkv_proj_kernel(const unsigned short* __restrict__ Xb, const unsigned short* __restrict__ Wb,
                     const float* __restrict__ bias,
                     unsigned short* __restrict__ Qb, unsigned short* __restrict__ Kb,
                     unsigned short* __restrict__ Vtb)
{
    const int z = blockIdx.z;
    // chunked XCD swizzle: each XCD gets 4 row-slabs x all 8 col tiles
    const int j   = blockIdx.x;           // 0..255
    const int xcd = j & 7, idx = j >> 3;  // idx 0..31
    const int row0 = ((xcd << 2) + (idx >> 3)) * 128;
    const int col0 = (idx & 7) * 128;
    const int wofs = z << 10;

    const unsigned short* A = Xb + (size_t)z * 4194304;
    const unsigned short* B = Wb;

    __shared__ __align__(16) unsigned short As[128 * 72];  // 64 + 8 pad
    __shared__ __align__(16) unsigned short Bs[128 * 72];

    const int tid  = threadIdx.x;
    const int lane = tid & 63;
    const int wv   = tid >> 6;
    const int wr   = wv >> 1, wc = wv & 1;

    const f32x4 zero4 = {0.f, 0.f, 0.f, 0.f};
    f32x4 acc[4][4];
#pragma unroll
    for (int m = 0; m < 4; ++m)
#pragma unroll
        for (int n = 0; n < 4; ++n) acc[m][n] = zero4;

    const int srow = tid >> 1;
    const int scol = (tid & 1) << 5;
    const int arow = wr * 64 + (lane & 15);
    const int brow = wc * 64 + (lane & 15);
    const int kof  = (lane >> 4) << 3;

    const unsigned short* pa = A + (size_t)(row0 + srow) * 1024 + scol;
    const unsigned short* pb = B + (size_t)(wofs + col0 + srow) * 1024 + scol;
    uint4 ra0 = *(const uint4*)(pa + 0),  ra1 = *(const uint4*)(pa + 8);
    uint4 ra2 = *(const uint4*)(pa + 16), ra3 = *(const uint4*)(pa + 24);
    uint4 rb0 = *(const uint4*)(pb + 0),  rb1 = *(const uint4*)(pb + 8);
    uint4 rb2 = *(const uint4*)(pb + 16), rb3 = *(const uint4*)(pb + 24);

    for (int k0 = 0; k0 < 1024; k0 += 64) {
        __syncthreads();
        *(uint4*)&As[srow * 72 + scol]      = ra0;
        *(uint4*)&As[srow * 72 + scol + 8]  = ra1;
        *(uint4*)&As[srow * 72 + scol + 16] = ra2;
        *(uint4*)&As[srow * 72 + scol + 24] = ra3;
        *(uint4*)&Bs[srow * 72 + scol]      = rb0;
        *(uint4*)&Bs[srow * 72 + scol + 8]  = rb1;
        *(uint4*)&Bs[srow * 72 + scol + 16] = rb2;
        *(uint4*)&Bs[srow * 72 + scol + 24] = rb3;
        __syncthreads();

        if (k0 < 960) {
            pa = A + (size_t)(row0 + srow) * 1024 + k0 + 64 + scol;
            pb = B + (size_t)(wofs + col0 + srow) * 1024 + k0 + 64 + scol;
            ra0 = *(const uint4*)(pa + 0);  ra1 = *(const uint4*)(pa + 8);
            ra2 = *(const uint4*)(pa + 16); ra3 = *(const uint4*)(pa + 24);
            rb0 = *(const uint4*)(pb + 0);  rb1 = *(const uint4*)(pb + 8);
            rb2 = *(const uint4*)(pb + 16); rb3 = *(const uint4*)(pb + 24);
        }

#pragma unroll
        for (int kk = 0; kk < 2; ++kk) {
            bf16x8 af[4], bfr[4];
#pragma unroll
            for (int m = 0; m < 4; ++m)
                af[m] = *(const bf16x8*)&As[(arow + m * 16) * 72 + kk * 32 + kof];
#pragma unroll
            for (int n = 0; n < 4; ++n)
                bfr[n] = *(const bf16x8*)&Bs[(brow + n * 16) * 72 + kk * 32 + kof];
#pragma unroll
            for (int m = 0; m < 4; ++m)
#pragma unroll
                for (int n = 0; n < 4; ++n)
                    acc[m][n] = __builtin_amdgcn_mfma_f32_16x16x32_bf16(af[m], bfr[n], acc[m][n], 0, 0, 0);
        }
    }

    const int ccol = lane & 15;
    const int crow = (lane >> 4) << 2;
#pragma unroll
    for (int n = 0; n < 4; ++n) {
        const int gc   = col0 + wc * 64 + n * 16 + ccol;
        const float bv = bias[wofs + gc];
        const int head = gc >> 6, d = gc & 63;
#pragma unroll
        for (int m = 0; m < 4; ++m) {
#pragma unroll
            for (int r = 0; r < 4; ++r) {
                const int gr = row0 + wr * 64 + m * 16 + crow + r;
                const int t  = gr >> 2, b = gr & 3;
                const int bh = (b << 4) + head;
                float vv = acc[m][n][r] + bv;
                if (z == 0)      Qb [((size_t)bh << 16) + ((size_t)t << 6) + d]  = f2bf(vv * QSCALE_F);
                else if (z == 1) Kb [((size_t)bh << 16) + ((size_t)t << 6) + d]  = f2bf(vv);
                else             Vtb[((size_t)bh << 16) + ((size_t)d << 10) + t] = f2bf(vv);
            }
        }
    }
}

// ===================== 2. flash attention (online softmax, log2-domain) =====================
__global__ __launch_bounds__(256)
void flash_kernel(const unsigned short* __restrict__ Qb, const unsigned short* __restrict__ Kb,
                  const unsigned short* __restrict__ Vtb, const float* __restrict__ attn_mask,
                  const int* __restrict__ padmask, float* __restrict__ m_buf,
                  float* __restrict__ rl_buf, unsigned short* __restrict__ attn_out)
{
    // chunked XCD swizzle: 8 consecutive bh per XCD (KV L2-resident)
    const int j   = blockIdx.x;              // 0..1023
    const int xcd = j & 7, idx = j >> 3;     // idx 0..127
    const int bh  = xcd * 8 + (idx >> 4);
    const int t0  = (idx & 15) << 6;
    const int b   = bh >> 4, h = bh & 15;

    __shared__ __align__(16) unsigned short Ks[64 * 72];
    __shared__ __align__(16) unsigned short Vs[64 * 72];
    __shared__ __align__(16) unsigned short Ps[64 * 72];

    const int tid  = threadIdx.x;
    const int lane = tid & 63;
    const int wv   = tid >> 6;
    const int kof  = (lane >> 4) << 3;
    const int c16  = lane & 15;

    const unsigned short* Qbase = Qb  + ((size_t)bh << 16);
    const unsigned short* Kbase = Kb  + ((size_t)bh << 16);
    const unsigned short* Vbase = Vtb + ((size_t)bh << 16);

    bf16x8 qf[2];
#pragma unroll
    for (int kk = 0; kk < 2; ++kk)
        qf[kk] = *(const bf16x8*)(Qbase + ((size_t)(t0 + wv * 16 + c16) << 6) + kk * 32 + kof);

    const f32x4 zero4 = {0.f, 0.f, 0.f, 0.f};
    f32x4 acco[4];
#pragma unroll
    for (int nd = 0; nd < 4; ++nd) acco[nd] = zero4;
    float mrow[4], lrow[4];
#pragma unroll
    for (int r = 0; r < 4; ++r) { mrow[r] = -1e30f; lrow[r] = 0.f; }

    const int srow_st = tid >> 2;
    const int scol_st = (tid & 3) << 4;

    const unsigned short* kp = Kbase + ((size_t)srow_st << 6) + scol_st;
    const unsigned short* vp = Vbase + ((size_t)srow_st << 10) + scol_st;
    uint4 kr0 = *(const uint4*)kp, kr1 = *(const uint4*)(kp + 8);
    uint4 vr0 = *(const uint4*)vp, vr1 = *(const uint4*)(vp + 8);

    for (int s0 = 0; s0 < 1024; s0 += 64) {
        __syncthreads();
        *(uint4*)&Ks[srow_st * 72 + scol_st]     = kr0;
        *(uint4*)&Ks[srow_st * 72 + scol_st + 8] = kr1;
        *(uint4*)&Vs[srow_st * 72 + scol_st]     = vr0;
        *(uint4*)&Vs[srow_st * 72 + scol_st + 8] = vr1;
        __syncthreads();

        if (s0 < 960) {
            kp = Kbase + ((size_t)(s0 + 64 + srow_st) << 6) + scol_st;
            vp = Vbase + ((size_t)srow_st << 10) + (s0 + 64) + scol_st;
            kr0 = *(const uint4*)kp; kr1 = *(const uint4*)(kp + 8);
            vr0 = *(const uint4*)vp; vr1 = *(const uint4*)(vp + 8);
        }

        f32x4 accs[4];
#pragma unroll
        for (int n = 0; n < 4; ++n) accs[n] = zero4;
#pragma unroll
        for (int n = 0; n < 4; ++n) {
            bf16x8 kf0 = *(const bf16x8*)&Ks[(n * 16 + c16) * 72 + kof];
            bf16x8 kf1 = *(const bf16x8*)&Ks[(n * 16 + c16) * 72 + 32 + kof];
            accs[n] = __builtin_amdgcn_mfma_f32_16x16x32_bf16(qf[0], kf0, accs[n], 0, 0, 0);
            accs[n] = __builtin_amdgcn_mfma_f32_16x16x32_bf16(qf[1], kf1, accs[n], 0, 0, 0);
        }

        int pad_s[4];
#pragma unroll
        for (int n = 0; n < 4; ++n)
            pad_s[n] = padmask[(b << 10) + s0 + n * 16 + c16];

        const int rbase = wv * 16 + ((lane >> 4) << 2);
#pragma unroll
        for (int r = 0; r < 4; ++r) {
            const float* mp = attn_mask + (size_t)(t0 + rbase + r) * 1024 + s0 + c16;
            float x0 = accs[0][r] + mp[ 0] * LOG2E_F;
            float x1 = accs[1][r] + mp[16] * LOG2E_F;
            float x2 = accs[2][r] + mp[32] * LOG2E_F;
            float x3 = accs[3][r] + mp[48] * LOG2E_F;
            if (pad_s[0]) x0 = -1e30f;
            if (pad_s[1]) x1 = -1e30f;
            if (pad_s[2]) x2 = -1e30f;
            if (pad_s[3]) x3 = -1e30f;
            float tmax = fmaxf(fmaxf(x0, x1), fmaxf(x2, x3));
            tmax = fmaxf(tmax, __shfl_xor(tmax, 1));
            tmax = fmaxf(tmax, __shfl_xor(tmax, 2));
            tmax = fmaxf(tmax, __shfl_xor(tmax, 4));
            tmax = fmaxf(tmax, __shfl_xor(tmax, 8));
            const float mold = mrow[r];
            const float mnew = fmaxf(mold, tmax);
            const float scale = exp2f(mold - mnew);
            float p0 = pad_s[0] ? 0.f : exp2f(x0 - mnew);
            float p1 = pad_s[1] ? 0.f : exp2f(x1 - mnew);
            float p2 = pad_s[2] ? 0.f : exp2f(x2 - mnew);
            float p3 = pad_s[3] ? 0.f : exp2f(x3 - mnew);
            float psum = p0 + p1 + p2 + p3;
            psum += __shfl_xor(psum, 1);
            psum += __shfl_xor(psum, 2);
            psum += __shfl_xor(psum, 4);
            psum += __shfl_xor(psum, 8);
            mrow[r] = mnew;
            lrow[r] = lrow[r] * scale + psum;
#pragma unroll
            for (int nd = 0; nd < 4; ++nd) acco[nd][r] *= scale;
            const int prow = rbase + r;
            Ps[prow * 72 +  0 + c16] = f2bf(p0);
            Ps[prow * 72 + 16 + c16] = f2bf(p1);
            Ps[prow * 72 + 32 + c16] = f2bf(p2);
            Ps[prow * 72 + 48 + c16] = f2bf(p3);
        }

#pragma unroll
        for (int kk2 = 0; kk2 < 2; ++kk2) {
            bf16x8 pf = *(const bf16x8*)&Ps[(wv * 16 + c16) * 72 + kk2 * 32 + kof];
#pragma unroll
            for (int nd = 0; nd < 4; ++nd) {
                bf16x8 vf = *(const bf16x8*)&Vs[(nd * 16 + c16) * 72 + kk2 * 32 + kof];
                acco[nd] = __builtin_amdgcn_mfma_f32_16x16x32_bf16(pf, vf, acco[nd], 0, 0, 0);
            }
        }
    }

#pragma unroll
    for (int r = 0; r < 4; ++r) {
        const int t = t0 + wv * 16 + ((lane >> 4) << 2) + r;
        const float rl = 1.0f / lrow[r];
        if (c16 == 0) {
            m_buf [(bh << 10) + t] = mrow[r];
            rl_buf[(bh << 10) + t] = rl;
        }
#pragma unroll
        for (int nd = 0; nd < 4; ++nd) {
            const int d = nd * 16 + c16;
            attn_out[((size_t)t * 4 + b) * 1024 + h * 64 + d] = f2bf(acco[nd][r] * rl);
        }
    }
}

// ===================== 3. weights_avg (recompute scores, all heads) =====================
__global__ __launch_bounds__(256)
void wavg_kernel(const unsigned short* __restrict__ Qb, const unsigned short* __restrict__ Kb,
                 const float* __restrict__ attn_mask, const int* __restrict__ padmask,
                 const float* __restrict__ m_buf, const float* __restrict__ rl_buf,
                 float* __restrict__ wout)
{
    // batch-partitioned XCD swizzle: batch b owns XCDs {2b, 2b+1}; Q+K per b L2-resident
    const int j   = blockIdx.x;              // 0..1023
    const int xcd = j & 7;
    const int b   = xcd >> 1;
    const int rr  = ((j >> 3) << 1) + (xcd & 1);  // 0..255
    const int t0  = (rr >> 4) << 6;
    const int s0  = (rr & 15) << 6;

    __shared__ __align__(16) unsigned short Qs[64 * 72];
    __shared__ __align__(16) unsigned short Ks2[64 * 72];

    const int tid  = threadIdx.x;
    const int lane = tid & 63;
    const int wv   = tid >> 6;
    const int wr   = wv >> 1, wc = wv & 1;
    const int kof  = (lane >> 4) << 3;
    const int srow_st = tid >> 2;
    const int scol_st = (tid & 3) << 4;

    const int t_base = t0 + wr * 32 + ((lane >> 4) << 2);
    const int s_base = s0 + wc * 32 + (lane & 15);

    int pad2[2];
#pragma unroll
    for (int nn = 0; nn < 2; ++nn) pad2[nn] = padmask[(b << 10) + s_base + nn * 16];

    float maskv[2][2][4];
#pragma unroll
    for (int mm = 0; mm < 2; ++mm)
#pragma unroll
        for (int r = 0; r < 4; ++r)
#pragma unroll
            for (int nn = 0; nn < 2; ++nn)
                maskv[mm][nn][r] = attn_mask[(size_t)(t_base + mm * 16 + r) * 1024 + s_base + nn * 16] * LOG2E_F;

    float wsum[2][2][4];
#pragma unroll
    for (int mm = 0; mm < 2; ++mm)
#pragma unroll
        for (int nn = 0; nn < 2; ++nn)
#pragma unroll
            for (int r = 0; r < 4; ++r) wsum[mm][nn][r] = 0.f;

    for (int h = 0; h < 16; ++h) {
        const int bh = (b << 4) + h;
        __syncthreads();
        {
            const unsigned short* qp = Qb + ((size_t)bh << 16) + ((size_t)(t0 + srow_st) << 6) + scol_st;
            *(uint4*)&Qs[srow_st * 72 + scol_st]     = *(const uint4*)qp;
            *(uint4*)&Qs[srow_st * 72 + scol_st + 8] = *(const uint4*)(qp + 8);
            const unsigned short* kp = Kb + ((size_t)bh << 16) + ((size_t)(s0 + srow_st) << 6) + scol_st;
            *(uint4*)&Ks2[srow_st * 72 + scol_st]     = *(const uint4*)kp;
            *(uint4*)&Ks2[srow_st * 72 + scol_st + 8] = *(const uint4*)(kp + 8);
        }
        __syncthreads();

        float mv[2][4], rlv[2][4];
#pragma unroll
        for (int mm = 0; mm < 2; ++mm)
#pragma unroll
            for (int r = 0; r < 4; ++r) {
                const int t = t_base + mm * 16 + r;
                mv [mm][r] = m_buf [(bh << 10) + t];
                rlv[mm][r] = rl_buf[(bh << 10) + t];
            }

        const f32x4 zero4 = {0.f, 0.f, 0.f, 0.f};
        f32x4 accs[2][2];
#pragma unroll
        for (int mm = 0; mm < 2; ++mm)
#pragma unroll
            for (int nn = 0; nn < 2; ++nn) accs[mm][nn] = zero4;
#pragma unroll
        for (int nn = 0; nn < 2; ++nn) {
            bf16x8 kf0 = *(const bf16x8*)&Ks2[(wc * 32 + nn * 16 + (lane & 15)) * 72 + kof];
            bf16x8 kf1 = *(const bf16x8*)&Ks2[(wc * 32 + nn * 16 + (lane & 15)) * 72 + 32 + kof];
#pragma unroll
            for (int mm = 0; mm < 2; ++mm) {
                bf16x8 qf0 = *(const bf16x8*)&Qs[(wr * 32 + mm * 16 + (lane & 15)) * 72 + kof];
                bf16x8 qf1 = *(const bf16x8*)&Qs[(wr * 32 + mm * 16 + (lane & 15)) * 72 + 32 + kof];
                accs[mm][nn] = __builtin_amdgcn_mfma_f32_16x16x32_bf16(qf0, kf0, accs[mm][nn], 0, 0, 0);
                accs[mm][nn] = __builtin_amdgcn_mfma_f32_16x16x32_bf16(qf1, kf1, accs[mm][nn], 0, 0, 0);
            }
        }
#pragma unroll
        for (int mm = 0; mm < 2; ++mm)
#pragma unroll
            for (int nn = 0; nn < 2; ++nn)
#pragma unroll
                for (int r = 0; r < 4; ++r)
                    if (!pad2[nn]) {
                        float x = accs[mm][nn][r] + maskv[mm][nn][r];
                        wsum[mm][nn][r] += exp2f(x - mv[mm][r]) * rlv[mm][r];
                    }
    }

#pragma unroll
    for (int mm = 0; mm < 2; ++mm)
#pragma unroll
        for (int nn = 0; nn < 2; ++nn)
#pragma unroll
            for (int r = 0; r < 4; ++r)
                wout[((size_t)b << 20) + (size_t)(t_base + mm * 16 + r) * 1024 + s_base + nn * 16]
                    = wsum[mm][nn][r] * 0.0625f;
}

// ===================== 4. out projection GEMM (bf16 A & W, BK=64, prefetch) =====================
__global__ __launch_bounds__(256)
void out_proj_kernel(const unsigned short* __restrict__ A, const unsigned short* __restrict__ Wb,
                     const float* __restrict__ bias, float* __restrict__ out)
{
    const int j   = blockIdx.x;           // 0..255
    const int xcd = j & 7, idx = j >> 3;
    const int row0 = ((xcd << 2) + (idx >> 3)) * 128;
    const int col0 = (idx & 7) * 128;

    __shared__ __align__(16) unsigned short As[128 * 72];
    __shared__ __align__(16) unsigned short Bs[128 * 72];

    const int tid  = threadIdx.x;
    const int lane = tid & 63;
    const int wv   = tid >> 6;
    const int wr   = wv >> 1, wc = wv & 1;

    const f32x4 zero4 = {0.f, 0.f, 0.f, 0.f};
    f32x4 acc[4][4];
#pragma unroll
    for (int m = 0; m < 4; ++m)
#pragma unroll
        for (int n = 0; n < 4; ++n) acc[m][n] = zero4;

    const int srow = tid >> 1;
    const int scol = (tid & 1) << 5;
    const int arow = wr * 64 + (lane & 15);
    const int brow = wc * 64 + (lane & 15);
    const int kof  = (lane >> 4) << 3;

    const unsigned short* pa = A  + (size_t)(row0 + srow) * 1024 + scol;
    const unsigned short* pb = Wb + (size_t)(col0 + srow) * 1024 + scol;
    uint4 ra0 = *(const uint4*)(pa + 0),  ra1 = *(const uint4*)(pa + 8);
    uint4 ra2 = *(const uint4*)(pa + 16), ra3 = *(const uint4*)(pa + 24);
    uint4 rb0 = *(const uint4*)(pb + 0),  rb1 = *(const uint4*)(pb + 8);
    uint4 rb2 = *(const uint4*)(pb + 16), rb3 = *(const uint4*)(pb + 24);

    for (int k0 = 0; k0 < 1024; k0 += 64) {
        __syncthreads();
        *(uint4*)&As[srow * 72 + scol]      = ra0;
        *(uint4*)&As[srow * 72 + scol + 8]  = ra1;
        *(uint4*)&As[srow * 72 + scol + 16] = ra2;
        *(uint4*)&As[srow * 72 + scol + 24] = ra3;
        *(uint4*)&Bs[srow * 72 + scol]      = rb0;
        *(uint4*)&Bs[srow * 72 + scol + 8]  = rb1;
        *(uint4*)&Bs[srow * 72 + scol + 16] = rb2;
        *(uint4*)&Bs[srow * 72 + scol + 24] = rb3;
        __syncthreads();

        if (k0 < 960) {
            pa = A  + (size_t)(row0 + srow) * 1024 + k0 + 64 + scol;
            pb = Wb + (size_t)(col0 + srow) * 1024 + k0 + 64 + scol;
            ra0 = *(const uint4*)(pa + 0);  ra1 = *(const uint4*)(pa + 8);
            ra2 = *(const uint4*)(pa + 16); ra3 = *(const uint4*)(pa + 24);
            rb0 = *(const uint4*)(pb + 0);  rb1 = *(const uint4*)(pb + 8);
            rb2 = *(const uint4*)(pb + 16); rb3 = *(const uint4*)(pb + 24);
        }

#pragma unroll
        for (int kk = 0; kk < 2; ++kk) {
            bf16x8 af[4], bfr[4];
#pragma unroll
            for (int m = 0; m < 4; ++m)
                af[m] = *(const bf16x8*)&As[(arow + m * 16) * 72 + kk * 32 + kof];
#pragma unroll
            for (int n = 0; n < 4; ++n)
                bfr[n] = *(const bf16x8*)&Bs[(brow + n * 16) * 72 + kk * 32 + kof];
#pragma unroll
            for (int m = 0; m < 4; ++m)
#pragma unroll
                for (int n = 0; n < 4; ++n)
                    acc[m][n] = __builtin_amdgcn_mfma_f32_16x16x32_bf16(af[m], bfr[n], acc[m][n], 0, 0, 0);
        }
    }

    const int ccol = lane & 15;
    const int crow = (lane >> 4) << 2;
#pragma unroll
    for (int n = 0; n < 4; ++n) {
        const int gc   = col0 + wc * 64 + n * 16 + ccol;
        const float bv = bias[gc];
#pragma unroll
        for (int m = 0; m < 4; ++m) {
#pragma unroll
            for (int r = 0; r < 4; ++r) {
                const int gr = row0 + wr * 64 + m * 16 + crow + r;
                out[(size_t)gr * 1024 + gc] = acc[m][n][r] + bv;
            }
        }
    }
}

// ===================== host =====================
extern "C" void kernel_launch(void* const* d_in, const int* in_sizes, int n_in,
                              void* d_out, int out_size, void* d_ws, size_t ws_size,
                              hipStream_t stream)
{
    const float* query     = (const float*)d_in[0];
    const float* key       = (const float*)d_in[1];
    const float* value     = (const float*)d_in[2];
    const float* attn_mask = (const float*)d_in[3];
    const int*   padmask   = (const int*)  d_in[4];
    const float* in_proj_w = (const float*)d_in[5];
    const float* in_proj_b = (const float*)d_in[6];
    const float* out_w     = (const float*)d_in[7];
    const float* out_b     = (const float*)d_in[8];

    float* out  = (float*)d_out;
    float* wavg = out + 4194304;

    char* ws = (char*)d_ws;
    unsigned short* Qb     = (unsigned short*)(ws);              // 8 MB  [64][1024][64]
    unsigned short* Kb     = (unsigned short*)(ws + 8388608);    // 8 MB
    unsigned short* Vtb    = (unsigned short*)(ws + 16777216);   // 8 MB  [64][64][1024]
    unsigned short* Xb     = (unsigned short*)(ws + 25165824);   // 24 MB (dead after qkv)
    unsigned short* attn_o = (unsigned short*)(ws + 25165824);   // 8 MB  aliases Xb
    unsigned short* Wb     = (unsigned short*)(ws + 50331648);   // 6 MB
    unsigned short* OWb    = (unsigned short*)(ws + 56623104);   // 2 MB
    float*          m_buf  = (float*)(ws + 58720256);            // 256 KB
    float*          rl_buf = (float*)(ws + 58982400);            // 256 KB

    cvt_kernel<<<dim3(8192), 256, 0, stream>>>(query, key, value, in_proj_w, out_w,
                                               (uint4*)Xb, (uint4*)Wb, (uint4*)OWb);
    qkv_proj_kernel<<<dim3(256, 1, 3), 256, 0, stream>>>(Xb, Wb, in_proj_b, Qb, Kb, Vtb);
    flash_kernel<<<dim3(1024), 256, 0, stream>>>(Qb, Kb, Vtb, attn_mask, padmask,
                                                 m_buf, rl_buf, attn_o);
    wavg_kernel<<<dim3(1024), 256, 0, stream>>>(Qb, Kb, attn_mask, padmask,
                                                m_buf, rl_buf, wavg);
    out_proj_kernel<<<dim3(256), 256, 0, stream>>>(attn_o, OWb, out_b, out);
}

// Round 4
// 158.597 us; speedup vs baseline: 1.6557x; 1.2242x over previous
//
#include <hip/hip_runtime.h>
#include <stdint.h>

typedef short bf16x8 __attribute__((ext_vector_type(8)));
typedef float f32x4  __attribute__((ext_vector_type(4)));

#define LOG2E_F 1.4426950408889634f
// 0.125 * log2(e): folded into Q so exp2 args need no multiply
#define QSCALE_F 0.1803368801111204f

__device__ __forceinline__ unsigned short f2bf(float f) {
    unsigned int u = __float_as_uint(f);
    return (unsigned short)((u + 0x7FFFu + ((u >> 16) & 1u)) >> 16);
}

// fast pack for non-negative, non-NaN values (round-half-up)
__device__ __forceinline__ unsigned short f2bfu(float f) {
    return (unsigned short)((__float_as_uint(f) + 0x8000u) >> 16);
}

__device__ __forceinline__ uint4 pack8(float4 a, float4 b) {
    union { unsigned short us[8]; uint4 v; } p;
    p.us[0] = f2bf(a.x); p.us[1] = f2bf(a.y); p.us[2] = f2bf(a.z); p.us[3] = f2bf(a.w);
    p.us[4] = f2bf(b.x); p.us[5] = f2bf(b.y); p.us[6] = f2bf(b.z); p.us[7] = f2bf(b.w);
    return p.v;
}

// ===================== 0. f32 -> bf16 convert (X, in_proj_w, out_w) =====================
__global__ __launch_bounds__(256)
void cvt_kernel(const float* __restrict__ q, const float* __restrict__ k,
                const float* __restrict__ v, const float* __restrict__ w,
                const float* __restrict__ ow,
                uint4* __restrict__ Xb, uint4* __restrict__ Wb, uint4* __restrict__ OWb)
{
    const unsigned g = blockIdx.x * 256 + threadIdx.x;   // 0 .. 2097151
    const float* src;
    uint4* dst;
    if (g < 1572864u) {
        dst = Xb + g;
        if (g < 524288u)        src = q + (size_t)g * 8;
        else if (g < 1048576u)  src = k + (size_t)(g - 524288u) * 8;
        else                    src = v + (size_t)(g - 1048576u) * 8;
    } else if (g < 1966080u) {
        src = w + (size_t)(g - 1572864u) * 8;
        dst = Wb + (g - 1572864u);
    } else {
        src = ow + (size_t)(g - 1966080u) * 8;
        dst = OWb + (g - 1966080u);
    }
    float4 a = *(const float4*)src;
    float4 b = *(const float4*)(src + 4);
    *dst = pack8(a, b);
}

// ===================== 1. QKV projection GEMM (bf16 in, BK=64, prefetch) =====================
__global__ __launch_bounds__(256)
void qkv_proj_kernel(const unsigned short* __restrict__ Xb, const unsigned short* __restrict__ Wb,
                     const float* __restrict__ bias,
                     unsigned short* __restrict__ Qb, unsigned short* __restrict__ Kb,
                     unsigned short* __restrict__ Vtb)
{
    const int z = blockIdx.z;
    const int j   = blockIdx.x;           // 0..255
    const int xcd = j & 7, idx = j >> 3;  // idx 0..31
    const int row0 = ((xcd << 2) + (idx >> 3)) * 128;
    const int col0 = (idx & 7) * 128;
    const int wofs = z << 10;

    const unsigned short* A = Xb + (size_t)z * 4194304;
    const unsigned short* B = Wb;

    __shared__ __align__(16) unsigned short As[128 * 72];
    __shared__ __align__(16) unsigned short Bs[128 * 72];

    const int tid  = threadIdx.x;
    const int lane = tid & 63;
    const int wv   = tid >> 6;
    const int wr   = wv >> 1, wc = wv & 1;

    const f32x4 zero4 = {0.f, 0.f, 0.f, 0.f};
    f32x4 acc[4][4];
#pragma unroll
    for (int m = 0; m < 4; ++m)
#pragma unroll
        for (int n = 0; n < 4; ++n) acc[m][n] = zero4;

    const int srow = tid >> 1;
    const int scol = (tid & 1) << 5;
    const int arow = wr * 64 + (lane & 15);
    const int brow = wc * 64 + (lane & 15);
    const int kof  = (lane >> 4) << 3;

    const unsigned short* pa = A + (size_t)(row0 + srow) * 1024 + scol;
    const unsigned short* pb = B + (size_t)(wofs + col0 + srow) * 1024 + scol;
    uint4 ra0 = *(const uint4*)(pa + 0),  ra1 = *(const uint4*)(pa + 8);
    uint4 ra2 = *(const uint4*)(pa + 16), ra3 = *(const uint4*)(pa + 24);
    uint4 rb0 = *(const uint4*)(pb + 0),  rb1 = *(const uint4*)(pb + 8);
    uint4 rb2 = *(const uint4*)(pb + 16), rb3 = *(const uint4*)(pb + 24);

    for (int k0 = 0; k0 < 1024; k0 += 64) {
        __syncthreads();
        *(uint4*)&As[srow * 72 + scol]      = ra0;
        *(uint4*)&As[srow * 72 + scol + 8]  = ra1;
        *(uint4*)&As[srow * 72 + scol + 16] = ra2;
        *(uint4*)&As[srow * 72 + scol + 24] = ra3;
        *(uint4*)&Bs[srow * 72 + scol]      = rb0;
        *(uint4*)&Bs[srow * 72 + scol + 8]  = rb1;
        *(uint4*)&Bs[srow * 72 + scol + 16] = rb2;
        *(uint4*)&Bs[srow * 72 + scol + 24] = rb3;
        __syncthreads();

        if (k0 < 960) {
            pa = A + (size_t)(row0 + srow) * 1024 + k0 + 64 + scol;
            pb = B + (size_t)(wofs + col0 + srow) * 1024 + k0 + 64 + scol;
            ra0 = *(const uint4*)(pa + 0);  ra1 = *(const uint4*)(pa + 8);
            ra2 = *(const uint4*)(pa + 16); ra3 = *(const uint4*)(pa + 24);
            rb0 = *(const uint4*)(pb + 0);  rb1 = *(const uint4*)(pb + 8);
            rb2 = *(const uint4*)(pb + 16); rb3 = *(const uint4*)(pb + 24);
        }

#pragma unroll
        for (int kk = 0; kk < 2; ++kk) {
            bf16x8 af[4], bfr[4];
#pragma unroll
            for (int m = 0; m < 4; ++m)
                af[m] = *(const bf16x8*)&As[(arow + m * 16) * 72 + kk * 32 + kof];
#pragma unroll
            for (int n = 0; n < 4; ++n)
                bfr[n] = *(const bf16x8*)&Bs[(brow + n * 16) * 72 + kk * 32 + kof];
#pragma unroll
            for (int m = 0; m < 4; ++m)
#pragma unroll
                for (int n = 0; n < 4; ++n)
                    acc[m][n] = __builtin_amdgcn_mfma_f32_16x16x32_bf16(af[m], bfr[n], acc[m][n], 0, 0, 0);
        }
    }

    const int ccol = lane & 15;
    const int crow = (lane >> 4) << 2;
#pragma unroll
    for (int n = 0; n < 4; ++n) {
        const int gc   = col0 + wc * 64 + n * 16 + ccol;
        const float bv = bias[wofs + gc];
        const int head = gc >> 6, d = gc & 63;
#pragma unroll
        for (int m = 0; m < 4; ++m) {
#pragma unroll
            for (int r = 0; r < 4; ++r) {
                const int gr = row0 + wr * 64 + m * 16 + crow + r;
                const int t  = gr >> 2, b = gr & 3;
                const int bh = (b << 4) + head;
                float vv = acc[m][n][r] + bv;
                if (z == 0)      Qb [((size_t)bh << 16) + ((size_t)t << 6) + d]  = f2bf(vv * QSCALE_F);
                else if (z == 1) Kb [((size_t)bh << 16) + ((size_t)t << 6) + d]  = f2bf(vv);
                else             Vtb[((size_t)bh << 16) + ((size_t)d << 10) + t] = f2bf(vv);
            }
        }
    }
}

// ===================== 2. flash attention (fixed-shift softmax, no reductions) =====================
// exp2-domain, shift C=0 (exact by softmax shift-invariance; |x|<~16 << f32 range).
// Row-sum l computed by MFMA against a ones B-operand -> zero cross-lane shuffles.
__global__ __launch_bounds__(256)
void flash_kernel(const unsigned short* __restrict__ Qb, const unsigned short* __restrict__ Kb,
                  const unsigned short* __restrict__ Vtb, const float* __restrict__ attn_mask,
                  const int* __restrict__ padmask,
                  float* __restrict__ rl_buf, unsigned short* __restrict__ attn_out)
{
    const int j   = blockIdx.x;              // 0..1023
    const int xcd = j & 7, idx = j >> 3;     // idx 0..127
    const int bh  = xcd * 8 + (idx >> 4);
    const int t0  = (idx & 15) << 6;
    const int b   = bh >> 4, h = bh & 15;

    __shared__ __align__(16) unsigned short Ks[64 * 72];
    __shared__ __align__(16) unsigned short Vs[64 * 72];
    __shared__ __align__(16) unsigned short Ps[64 * 72];

    const int tid  = threadIdx.x;
    const int lane = tid & 63;
    const int wv   = tid >> 6;
    const int kof  = (lane >> 4) << 3;
    const int c16  = lane & 15;

    const unsigned short* Qbase = Qb  + ((size_t)bh << 16);
    const unsigned short* Kbase = Kb  + ((size_t)bh << 16);
    const unsigned short* Vbase = Vtb + ((size_t)bh << 16);

    bf16x8 qf[2];
#pragma unroll
    for (int kk = 0; kk < 2; ++kk)
        qf[kk] = *(const bf16x8*)(Qbase + ((size_t)(t0 + wv * 16 + c16) << 6) + kk * 32 + kof);

    const bf16x8 ones = {16256, 16256, 16256, 16256, 16256, 16256, 16256, 16256}; // 8x bf16 1.0

    const f32x4 zero4 = {0.f, 0.f, 0.f, 0.f};
    f32x4 acco[4];
#pragma unroll
    for (int nd = 0; nd < 4; ++nd) acco[nd] = zero4;
    f32x4 acc_l = zero4;   // row-sums via ones-MFMA

    const int srow_st = tid >> 2;
    const int scol_st = (tid & 3) << 4;

    const unsigned short* kp = Kbase + ((size_t)srow_st << 6) + scol_st;
    const unsigned short* vp = Vbase + ((size_t)srow_st << 10) + scol_st;
    uint4 kr0 = *(const uint4*)kp, kr1 = *(const uint4*)(kp + 8);
    uint4 vr0 = *(const uint4*)vp, vr1 = *(const uint4*)(vp + 8);

    for (int s0 = 0; s0 < 1024; s0 += 64) {
        __syncthreads();
        *(uint4*)&Ks[srow_st * 72 + scol_st]     = kr0;
        *(uint4*)&Ks[srow_st * 72 + scol_st + 8] = kr1;
        *(uint4*)&Vs[srow_st * 72 + scol_st]     = vr0;
        *(uint4*)&Vs[srow_st * 72 + scol_st + 8] = vr1;
        __syncthreads();

        if (s0 < 960) {
            kp = Kbase + ((size_t)(s0 + 64 + srow_st) << 6) + scol_st;
            vp = Vbase + ((size_t)srow_st << 10) + (s0 + 64) + scol_st;
            kr0 = *(const uint4*)kp; kr1 = *(const uint4*)(kp + 8);
            vr0 = *(const uint4*)vp; vr1 = *(const uint4*)(vp + 8);
        }

        f32x4 accs[4];
#pragma unroll
        for (int n = 0; n < 4; ++n) accs[n] = zero4;
#pragma unroll
        for (int n = 0; n < 4; ++n) {
            bf16x8 kf0 = *(const bf16x8*)&Ks[(n * 16 + c16) * 72 + kof];
            bf16x8 kf1 = *(const bf16x8*)&Ks[(n * 16 + c16) * 72 + 32 + kof];
            accs[n] = __builtin_amdgcn_mfma_f32_16x16x32_bf16(qf[0], kf0, accs[n], 0, 0, 0);
            accs[n] = __builtin_amdgcn_mfma_f32_16x16x32_bf16(qf[1], kf1, accs[n], 0, 0, 0);
        }

        int pad_s[4];
#pragma unroll
        for (int n = 0; n < 4; ++n)
            pad_s[n] = padmask[(b << 10) + s0 + n * 16 + c16];

        const int rbase = wv * 16 + ((lane >> 4) << 2);
#pragma unroll
        for (int r = 0; r < 4; ++r) {
            const float* mp = attn_mask + (size_t)(t0 + rbase + r) * 1024 + s0 + c16;
            float x0 = fmaf(mp[ 0], LOG2E_F, accs[0][r]);
            float x1 = fmaf(mp[16], LOG2E_F, accs[1][r]);
            float x2 = fmaf(mp[32], LOG2E_F, accs[2][r]);
            float x3 = fmaf(mp[48], LOG2E_F, accs[3][r]);
            if (pad_s[0]) x0 = -1e30f;
            if (pad_s[1]) x1 = -1e30f;
            if (pad_s[2]) x2 = -1e30f;
            if (pad_s[3]) x3 = -1e30f;
            const float p0 = __builtin_amdgcn_exp2f(x0);
            const float p1 = __builtin_amdgcn_exp2f(x1);
            const float p2 = __builtin_amdgcn_exp2f(x2);
            const float p3 = __builtin_amdgcn_exp2f(x3);
            const int prow = rbase + r;
            Ps[prow * 72 +  0 + c16] = f2bfu(p0);
            Ps[prow * 72 + 16 + c16] = f2bfu(p1);
            Ps[prow * 72 + 32 + c16] = f2bfu(p2);
            Ps[prow * 72 + 48 + c16] = f2bfu(p3);
        }
        // no barrier: each wave reads only its own Ps rows

#pragma unroll
        for (int kk2 = 0; kk2 < 2; ++kk2) {
            bf16x8 pf = *(const bf16x8*)&Ps[(wv * 16 + c16) * 72 + kk2 * 32 + kof];
#pragma unroll
            for (int nd = 0; nd < 4; ++nd) {
                bf16x8 vf = *(const bf16x8*)&Vs[(nd * 16 + c16) * 72 + kk2 * 32 + kof];
                acco[nd] = __builtin_amdgcn_mfma_f32_16x16x32_bf16(pf, vf, acco[nd], 0, 0, 0);
            }
            acc_l = __builtin_amdgcn_mfma_f32_16x16x32_bf16(pf, ones, acc_l, 0, 0, 0);
        }
    }

#pragma unroll
    for (int r = 0; r < 4; ++r) {
        const int t = t0 + wv * 16 + ((lane >> 4) << 2) + r;
        const float rl = 1.0f / acc_l[r];
        if (c16 == 0)
            rl_buf[(bh << 10) + t] = rl;
#pragma unroll
        for (int nd = 0; nd < 4; ++nd) {
            const int d = nd * 16 + c16;
            attn_out[((size_t)t * 4 + b) * 1024 + h * 64 + d] = f2bf(acco[nd][r] * rl);
        }
    }
}

// ===================== 3. weights_avg (recompute scores, all heads) =====================
__global__ __launch_bounds__(256)
void wavg_kernel(const unsigned short* __restrict__ Qb, const unsigned short* __restrict__ Kb,
                 const float* __restrict__ attn_mask, const int* __restrict__ padmask,
                 const float* __restrict__ rl_buf, float* __restrict__ wout)
{
    const int j   = blockIdx.x;              // 0..1023
    const int xcd = j & 7;
    const int b   = xcd >> 1;
    const int rr  = ((j >> 3) << 1) + (xcd & 1);  // 0..255
    const int t0  = (rr >> 4) << 6;
    const int s0  = (rr & 15) << 6;

    __shared__ __align__(16) unsigned short Qs[64 * 72];
    __shared__ __align__(16) unsigned short Ks2[64 * 72];

    const int tid  = threadIdx.x;
    const int lane = tid & 63;
    const int wv   = tid >> 6;
    const int wr   = wv >> 1, wc = wv & 1;
    const int kof  = (lane >> 4) << 3;
    const int srow_st = tid >> 2;
    const int scol_st = (tid & 3) << 4;

    const int t_base = t0 + wr * 32 + ((lane >> 4) << 2);
    const int s_base = s0 + wc * 32 + (lane & 15);

    int pad2[2];
#pragma unroll
    for (int nn = 0; nn < 2; ++nn) pad2[nn] = padmask[(b << 10) + s_base + nn * 16];

    float maskv[2][2][4];
#pragma unroll
    for (int mm = 0; mm < 2; ++mm)
#pragma unroll
        for (int r = 0; r < 4; ++r)
#pragma unroll
            for (int nn = 0; nn < 2; ++nn)
                maskv[mm][nn][r] = attn_mask[(size_t)(t_base + mm * 16 + r) * 1024 + s_base + nn * 16] * LOG2E_F;

    float wsum[2][2][4];
#pragma unroll
    for (int mm = 0; mm < 2; ++mm)
#pragma unroll
        for (int nn = 0; nn < 2; ++nn)
#pragma unroll
            for (int r = 0; r < 4; ++r) wsum[mm][nn][r] = 0.f;

    for (int h = 0; h < 16; ++h) {
        const int bh = (b << 4) + h;
        __syncthreads();
        {
            const unsigned short* qp = Qb + ((size_t)bh << 16) + ((size_t)(t0 + srow_st) << 6) + scol_st;
            *(uint4*)&Qs[srow_st * 72 + scol_st]     = *(const uint4*)qp;
            *(uint4*)&Qs[srow_st * 72 + scol_st + 8] = *(const uint4*)(qp + 8);
            const unsigned short* kp = Kb + ((size_t)bh << 16) + ((size_t)(s0 + srow_st) << 6) + scol_st;
            *(uint4*)&Ks2[srow_st * 72 + scol_st]     = *(const uint4*)kp;
            *(uint4*)&Ks2[srow_st * 72 + scol_st + 8] = *(const uint4*)(kp + 8);
        }
        __syncthreads();

        float rlv[2][4];
#pragma unroll
        for (int mm = 0; mm < 2; ++mm)
#pragma unroll
            for (int r = 0; r < 4; ++r)
                rlv[mm][r] = rl_buf[(bh << 10) + t_base + mm * 16 + r];

        const f32x4 zero4 = {0.f, 0.f, 0.f, 0.f};
        f32x4 accs[2][2];
#pragma unroll
        for (int mm = 0; mm < 2; ++mm)
#pragma unroll
            for (int nn = 0; nn < 2; ++nn) accs[mm][nn] = zero4;
#pragma unroll
        for (int nn = 0; nn < 2; ++nn) {
            bf16x8 kf0 = *(const bf16x8*)&Ks2[(wc * 32 + nn * 16 + (lane & 15)) * 72 + kof];
            bf16x8 kf1 = *(const bf16x8*)&Ks2[(wc * 32 + nn * 16 + (lane & 15)) * 72 + 32 + kof];
#pragma unroll
            for (int mm = 0; mm < 2; ++mm) {
                bf16x8 qf0 = *(const bf16x8*)&Qs[(wr * 32 + mm * 16 + (lane & 15)) * 72 + kof];
                bf16x8 qf1 = *(const bf16x8*)&Qs[(wr * 32 + mm * 16 + (lane & 15)) * 72 + 32 + kof];
                accs[mm][nn] = __builtin_amdgcn_mfma_f32_16x16x32_bf16(qf0, kf0, accs[mm][nn], 0, 0, 0);
                accs[mm][nn] = __builtin_amdgcn_mfma_f32_16x16x32_bf16(qf1, kf1, accs[mm][nn], 0, 0, 0);
            }
        }
#pragma unroll
        for (int mm = 0; mm < 2; ++mm)
#pragma unroll
            for (int nn = 0; nn < 2; ++nn)
#pragma unroll
                for (int r = 0; r < 4; ++r)
                    if (!pad2[nn]) {
                        float x = accs[mm][nn][r] + maskv[mm][nn][r];
                        wsum[mm][nn][r] += __builtin_amdgcn_exp2f(x) * rlv[mm][r];
                    }
    }

#pragma unroll
    for (int mm = 0; mm < 2; ++mm)
#pragma unroll
        for (int nn = 0; nn < 2; ++nn)
#pragma unroll
            for (int r = 0; r < 4; ++r)
                wout[((size_t)b << 20) + (size_t)(t_base + mm * 16 + r) * 1024 + s_base + nn * 16]
                    = wsum[mm][nn][r] * 0.0625f;
}

// ===================== 4. out projection GEMM (bf16 A & W, BK=64, prefetch) =====================
__global__ __launch_bounds__(256)
void out_proj_kernel(const unsigned short* __restrict__ A, const unsigned short* __restrict__ Wb,
                     const float* __restrict__ bias, float* __restrict__ out)
{
    const int j   = blockIdx.x;           // 0..255
    const int xcd = j & 7, idx = j >> 3;
    const int row0 = ((xcd << 2) + (idx >> 3)) * 128;
    const int col0 = (idx & 7) * 128;

    __shared__ __align__(16) unsigned short As[128 * 72];
    __shared__ __align__(16) unsigned short Bs[128 * 72];

    const int tid  = threadIdx.x;
    const int lane = tid & 63;
    const int wv   = tid >> 6;
    const int wr   = wv >> 1, wc = wv & 1;

    const f32x4 zero4 = {0.f, 0.f, 0.f, 0.f};
    f32x4 acc[4][4];
#pragma unroll
    for (int m = 0; m < 4; ++m)
#pragma unroll
        for (int n = 0; n < 4; ++n) acc[m][n] = zero4;

    const int srow = tid >> 1;
    const int scol = (tid & 1) << 5;
    const int arow = wr * 64 + (lane & 15);
    const int brow = wc * 64 + (lane & 15);
    const int kof  = (lane >> 4) << 3;

    const unsigned short* pa = A  + (size_t)(row0 + srow) * 1024 + scol;
    const unsigned short* pb = Wb + (size_t)(col0 + srow) * 1024 + scol;
    uint4 ra0 = *(const uint4*)(pa + 0),  ra1 = *(const uint4*)(pa + 8);
    uint4 ra2 = *(const uint4*)(pa + 16), ra3 = *(const uint4*)(pa + 24);
    uint4 rb0 = *(const uint4*)(pb + 0),  rb1 = *(const uint4*)(pb + 8);
    uint4 rb2 = *(const uint4*)(pb + 16), rb3 = *(const uint4*)(pb + 24);

    for (int k0 = 0; k0 < 1024; k0 += 64) {
        __syncthreads();
        *(uint4*)&As[srow * 72 + scol]      = ra0;
        *(uint4*)&As[srow * 72 + scol + 8]  = ra1;
        *(uint4*)&As[srow * 72 + scol + 16] = ra2;
        *(uint4*)&As[srow * 72 + scol + 24] = ra3;
        *(uint4*)&Bs[srow * 72 + scol]      = rb0;
        *(uint4*)&Bs[srow * 72 + scol + 8]  = rb1;
        *(uint4*)&Bs[srow * 72 + scol + 16] = rb2;
        *(uint4*)&Bs[srow * 72 + scol + 24] = rb3;
        __syncthreads();

        if (k0 < 960) {
            pa = A  + (size_t)(row0 + srow) * 1024 + k0 + 64 + scol;
            pb = Wb + (size_t)(col0 + srow) * 1024 + k0 + 64 + scol;
            ra0 = *(const uint4*)(pa + 0);  ra1 = *(const uint4*)(pa + 8);
            ra2 = *(const uint4*)(pa + 16); ra3 = *(const uint4*)(pa + 24);
            rb0 = *(const uint4*)(pb + 0);  rb1 = *(const uint4*)(pb + 8);
            rb2 = *(const uint4*)(pb + 16); rb3 = *(const uint4*)(pb + 24);
        }

#pragma unroll
        for (int kk = 0; kk < 2; ++kk) {
            bf16x8 af[4], bfr[4];
#pragma unroll
            for (int m = 0; m < 4; ++m)
                af[m] = *(const bf16x8*)&As[(arow + m * 16) * 72 + kk * 32 + kof];
#pragma unroll
            for (int n = 0; n < 4; ++n)
                bfr[n] = *(const bf16x8*)&Bs[(brow + n * 16) * 72 + kk * 32 + kof];
#pragma unroll
            for (int m = 0; m < 4; ++m)
#pragma unroll
                for (int n = 0; n < 4; ++n)
                    acc[m][n] = __builtin_amdgcn_mfma_f32_16x16x32_bf16(af[m], bfr[n], acc[m][n], 0, 0, 0);
        }
    }

    const int ccol = lane & 15;
    const int crow = (lane >> 4) << 2;
#pragma unroll
    for (int n = 0; n < 4; ++n) {
        const int gc   = col0 + wc * 64 + n * 16 + ccol;
        const float bv = bias[gc];
#pragma unroll
        for (int m = 0; m < 4; ++m) {
#pragma unroll
            for (int r = 0; r < 4; ++r) {
                const int gr = row0 + wr * 64 + m * 16 + crow + r;
                out[(size_t)gr * 1024 + gc] = acc[m][n][r] + bv;
            }
        }
    }
}

// ===================== host =====================
extern "C" void kernel_launch(void* const* d_in, const int* in_sizes, int n_in,
                              void* d_out, int out_size, void* d_ws, size_t ws_size,
                              hipStream_t stream)
{
    const float* query     = (const float*)d_in[0];
    const float* key       = (const float*)d_in[1];
    const float* value     = (const float*)d_in[2];
    const float* attn_mask = (const float*)d_in[3];
    const int*   padmask   = (const int*)  d_in[4];
    const float* in_proj_w = (const float*)d_in[5];
    const float* in_proj_b = (const float*)d_in[6];
    const float* out_w     = (const float*)d_in[7];
    const float* out_b     = (const float*)d_in[8];

    float* out  = (float*)d_out;
    float* wavg = out + 4194304;

    char* ws = (char*)d_ws;
    unsigned short* Qb     = (unsigned short*)(ws);              // 8 MB  [64][1024][64]
    unsigned short* Kb     = (unsigned short*)(ws + 8388608);    // 8 MB
    unsigned short* Vtb    = (unsigned short*)(ws + 16777216);   // 8 MB  [64][64][1024]
    unsigned short* Xb     = (unsigned short*)(ws + 25165824);   // 24 MB (dead after qkv)
    unsigned short* attn_o = (unsigned short*)(ws + 25165824);   // 8 MB  aliases Xb
    unsigned short* Wb     = (unsigned short*)(ws + 50331648);   // 6 MB
    unsigned short* OWb    = (unsigned short*)(ws + 56623104);   // 2 MB
    float*          rl_buf = (float*)(ws + 58720256);            // 256 KB

    cvt_kernel<<<dim3(8192), 256, 0, stream>>>(query, key, value, in_proj_w, out_w,
                                               (uint4*)Xb, (uint4*)Wb, (uint4*)OWb);
    qkv_proj_kernel<<<dim3(256, 1, 3), 256, 0, stream>>>(Xb, Wb, in_proj_b, Qb, Kb, Vtb);
    flash_kernel<<<dim3(1024), 256, 0, stream>>>(Qb, Kb, Vtb, attn_mask, padmask,
                                                 rl_buf, attn_o);
    wavg_kernel<<<dim3(1024), 256, 0, stream>>>(Qb, Kb, attn_mask, padmask,
                                                rl_buf, wavg);
    out_proj_kernel<<<dim3(256), 256, 0, stream>>>(attn_o, OWb, out_b, out);
}